// Round 1
// baseline (181.312 us; speedup 1.0000x reference)
//
#include <hip/hip_runtime.h>
#include <cstdint>
#include <cstddef>

#define DIMX 512
#define HDIM 32
#define NHEADS 16
#define SEQ 2048
#define BATCH 2
#define MTOT (BATCH*SEQ)   // 4096
#define WIN 64
#define QSCALE 0.17677669529663687f  // 32^-0.5

typedef __bf16 bf16x8 __attribute__((ext_vector_type(8)));
typedef float f32x4 __attribute__((ext_vector_type(4)));

__device__ __forceinline__ unsigned short f2bf(float f){
  unsigned u = __builtin_bit_cast(unsigned, f);
  u += 0x7FFFu + ((u >> 16) & 1u);          // RNE
  return (unsigned short)(u >> 16);
}
__device__ __forceinline__ float bf2f(unsigned short s){
  return __builtin_bit_cast(float, ((unsigned)s) << 16);
}
__device__ __forceinline__ unsigned pk(float a, float b){
  return (unsigned)f2bf(a) | ((unsigned)f2bf(b) << 16);
}

// ---------- K0a: fp32 -> bf16, 8 elems/thread ----------
__global__ void k_cvt(const float* __restrict__ src, unsigned short* __restrict__ dst, int n8){
  int i = blockIdx.x * blockDim.x + threadIdx.x;
  if (i >= n8) return;
  const float4* p = (const float4*)src + (size_t)i * 2;
  float4 a = p[0], b = p[1];
  uint4 o;
  o.x = pk(a.x, a.y); o.y = pk(a.z, a.w);
  o.z = pk(b.x, b.y); o.w = pk(b.z, b.w);
  ((uint4*)dst)[i] = o;
}

// ---------- K0b: W (K x N fp32) -> Wt (N x K bf16) ----------
__global__ void k_twt(const float* __restrict__ W, unsigned short* __restrict__ Wt, int K, int N){
  __shared__ float tile[32][33];
  int n0 = blockIdx.x * 32, k0 = blockIdx.y * 32;
  int tx = threadIdx.x, ty = threadIdx.y;   // block 32x8
  #pragma unroll
  for (int r = 0; r < 32; r += 8)
    tile[ty + r][tx] = W[(size_t)(k0 + ty + r) * N + n0 + tx];
  __syncthreads();
  #pragma unroll
  for (int r = 0; r < 32; r += 8)
    Wt[(size_t)(n0 + ty + r) * K + k0 + tx] = f2bf(tile[tx][ty + r]);
}

// ---------- K1/K4: bf16 MFMA GEMM, A[M][512] * Bt[N][512]^T ----------
// 128x128 tile, BK=64, 4 waves (2x2 of 64x64), XOR-swizzled LDS.
// mode 0: qkv epilogue (silu*scale -> qb, tanh -> kb, identity -> vb)
// mode 1: out proj epilogue: y = acc + bias + xres (fp32)
__launch_bounds__(256)
__global__ void k_gemm(const unsigned short* __restrict__ A,
                       const unsigned short* __restrict__ Bt,
                       const float* __restrict__ bias,
                       int mode,
                       unsigned short* __restrict__ qb,
                       unsigned short* __restrict__ kb,
                       unsigned short* __restrict__ vb,
                       const float* __restrict__ xres,
                       float* __restrict__ y)
{
  const int K = 512;
  __shared__ uint4 As[128 * 8];   // [row][chunk^(row&7)] chunks of 8 bf16
  __shared__ uint4 Bs[128 * 8];
  int tid = threadIdx.x;
  int wid = tid >> 6, lane = tid & 63;
  int wm = wid >> 1, wn = wid & 1;
  int bm = blockIdx.x, bn = blockIdx.y;
  int lane15 = lane & 15, laneh = lane >> 4;

  f32x4 acc[4][4] = {};
  int srow = tid >> 1, shalf = tid & 1;

  for (int kt = 0; kt < K / 64; ++kt){
    int k0 = kt * 64;
    uint4 av[4], bv[4];
    const uint4* ap = (const uint4*)(A  + (size_t)(bm * 128 + srow) * K + k0 + shalf * 32);
    const uint4* bp = (const uint4*)(Bt + (size_t)(bn * 128 + srow) * K + k0 + shalf * 32);
    #pragma unroll
    for (int c = 0; c < 4; ++c){ av[c] = ap[c]; bv[c] = bp[c]; }
    __syncthreads();   // previous compute done before overwrite
    #pragma unroll
    for (int c = 0; c < 4; ++c){
      int chunk = shalf * 4 + c;
      As[srow * 8 + (chunk ^ (srow & 7))] = av[c];
      Bs[srow * 8 + (chunk ^ (srow & 7))] = bv[c];
    }
    __syncthreads();
    #pragma unroll
    for (int kh = 0; kh < 2; ++kh){
      int chunk = kh * 4 + laneh;
      bf16x8 avf[4], bvf[4];
      #pragma unroll
      for (int mi = 0; mi < 4; ++mi){
        int row = wm * 64 + mi * 16 + lane15;
        avf[mi] = *(const bf16x8*)&As[row * 8 + (chunk ^ (row & 7))];
      }
      #pragma unroll
      for (int ni = 0; ni < 4; ++ni){
        int row = wn * 64 + ni * 16 + lane15;
        bvf[ni] = *(const bf16x8*)&Bs[row * 8 + (chunk ^ (row & 7))];
      }
      #pragma unroll
      for (int mi = 0; mi < 4; ++mi)
        #pragma unroll
        for (int ni = 0; ni < 4; ++ni)
          acc[mi][ni] = __builtin_amdgcn_mfma_f32_16x16x32_bf16(avf[mi], bvf[ni], acc[mi][ni], 0, 0, 0);
    }
  }

  #pragma unroll
  for (int mi = 0; mi < 4; ++mi){
    #pragma unroll
    for (int ni = 0; ni < 4; ++ni){
      #pragma unroll
      for (int r = 0; r < 4; ++r){
        int m = bm * 128 + wm * 64 + mi * 16 + laneh * 4 + r;
        int n = bn * 128 + wn * 64 + ni * 16 + lane15;
        float val = acc[mi][ni][r] + bias[n];
        if (mode == 0){
          if (n < DIMX){
            float s = val / (1.0f + __expf(-val)) * QSCALE;  // silu * scale
            float t = tanhf(val);
            qb[(size_t)m * DIMX + n] = f2bf(s);
            kb[(size_t)m * DIMX + n] = f2bf(t);
          } else {
            vb[(size_t)m * DIMX + (n - DIMX)] = f2bf(val);
          }
        } else {
          size_t idx = (size_t)m * DIMX + n;
          y[idx] = val + xres[idx];
        }
      }
    }
  }
}

// ---------- K2a: v [m][512] -> vt [bh*32+d][2048] (bf16) ----------
__global__ void k_vt(const unsigned short* __restrict__ vb, unsigned short* __restrict__ vt){
  __shared__ unsigned short tile[256][34];  // pad to kill bank conflicts
  int sc = blockIdx.x;        // 0..7  (256-row s chunk)
  int bh = blockIdx.y;        // 0..31
  int b = bh >> 4, h = bh & 15;
  int tid = threadIdx.x;
  int d = tid & 31, si = tid >> 5;
  #pragma unroll
  for (int i = 0; i < 32; ++i){
    int sl = i * 8 + si;
    tile[sl][d] = vb[(size_t)(b * SEQ + sc * 256 + sl) * DIMX + h * HDIM + d];
  }
  __syncthreads();
  int d2 = tid >> 6, s2 = tid & 63;
  #pragma unroll
  for (int i = 0; i < 8; ++i){
    int dd = i * 4 + d2;
    vt[(size_t)(bh * HDIM + dd) * SEQ + sc * 256 + s2] = tile[s2][dd];
  }
}

// ---------- K2b: vsum[bh][d] = sum_s v ----------
__global__ void k_vsum(const unsigned short* __restrict__ vb, float* __restrict__ vsum){
  int bh = blockIdx.x; int b = bh >> 4, h = bh & 15;
  int tid = threadIdx.x; int d = tid & 31, si = tid >> 5;
  float acc = 0.f;
  for (int s = si; s < SEQ; s += 8)
    acc += bf2f(vb[(size_t)(b * SEQ + s) * DIMX + h * HDIM + d]);
  __shared__ float red[8][32];
  red[si][d] = acc;
  __syncthreads();
  if (tid < 32){
    float t = 0.f;
    #pragma unroll
    for (int i = 0; i < 8; ++i) t += red[i][tid];
    vsum[bh * HDIM + tid] = t;
  }
}

// ---------- K3: banded attention (e^s - 1 trick), MFMA ----------
__launch_bounds__(256)
__global__ void k_attn(const unsigned short* __restrict__ qb,
                       const unsigned short* __restrict__ kb,
                       const unsigned short* __restrict__ vt,
                       const float* __restrict__ vsum,
                       unsigned short* __restrict__ ao)
{
  __shared__ unsigned short p_lds[4][16][40];   // per-wave P staging, padded
  int tid = threadIdx.x, wid = tid >> 6, lane = tid & 63;
  int lane15 = lane & 15, laneh = lane >> 4;
  int bh = blockIdx.y, b = bh >> 4, h = bh & 15;
  int s0 = blockIdx.x * 64 + wid * 16;

  bf16x8 qf = *(const bf16x8*)(qb + (size_t)(b * SEQ + s0 + lane15) * DIMX + h * HDIM + laneh * 8);
  float vs0 = vsum[bh * HDIM + lane15];
  float vs1 = vsum[bh * HDIM + 16 + lane15];

  f32x4 accv[2] = {};
  float dsum[4] = {0.f, 0.f, 0.f, 0.f};

  for (int jt = 0; jt < 10; ++jt){
    int j0 = s0 - 64 + jt * 16;
    int jr = j0 + lane15;
    int jc = min(max(jr, 0), SEQ - 1);
    bf16x8 kf = *(const bf16x8*)(kb + (size_t)(b * SEQ + jc) * DIMX + h * HDIM + laneh * 8);
    f32x4 z = {0.f, 0.f, 0.f, 0.f};
    f32x4 sv = __builtin_amdgcn_mfma_f32_16x16x32_bf16(qf, kf, z, 0, 0, 0);
    #pragma unroll
    for (int r = 0; r < 4; ++r){
      int i = s0 + laneh * 4 + r;
      int j = j0 + lane15;
      int dj = i - j;
      bool inb = (dj <= WIN) && (dj >= -WIN) && (j >= 0) && (j < SEQ);
      float w = inb ? (__expf(sv[r]) - 1.0f) : 0.0f;
      dsum[r] += w;
      p_lds[wid][laneh * 4 + r][(jt & 1) * 16 + lane15] = f2bf(w);
    }
    if (jt & 1){
      int jc0 = j0 - 16;   // 32-wide chunk base
      bf16x8 pa = *(const bf16x8*)&p_lds[wid][lane15][laneh * 8];
      int jv = min(max(jc0 + laneh * 8, 0), SEQ - 8);
      bf16x8 v0 = *(const bf16x8*)(vt + (size_t)(bh * HDIM + lane15) * SEQ + jv);
      bf16x8 v1 = *(const bf16x8*)(vt + (size_t)(bh * HDIM + 16 + lane15) * SEQ + jv);
      accv[0] = __builtin_amdgcn_mfma_f32_16x16x32_bf16(pa, v0, accv[0], 0, 0, 0);
      accv[1] = __builtin_amdgcn_mfma_f32_16x16x32_bf16(pa, v1, accv[1], 0, 0, 0);
    }
  }

  #pragma unroll
  for (int r = 0; r < 4; ++r){
    float v = dsum[r];
    v += __shfl_xor(v, 1); v += __shfl_xor(v, 2);
    v += __shfl_xor(v, 4); v += __shfl_xor(v, 8);
    dsum[r] = v;
  }
  #pragma unroll
  for (int r = 0; r < 4; ++r){
    int i = s0 + laneh * 4 + r;
    float dn = (float)SEQ + dsum[r];
    float o0 = (accv[0][r] + vs0) / dn;
    float o1 = (accv[1][r] + vs1) / dn;
    size_t base = (size_t)(b * SEQ + i) * DIMX + h * HDIM;
    ao[base + lane15]      = f2bf(o0);
    ao[base + 16 + lane15] = f2bf(o1);
  }
}

// ---------- K5: LayerNorm over 512, one wave per row ----------
__global__ void k_ln(const float* __restrict__ y, const float* __restrict__ gamma,
                     const float* __restrict__ beta, float* __restrict__ out){
  int wid = threadIdx.x >> 6, lane = threadIdx.x & 63;
  int row = blockIdx.x * 4 + wid;
  const float4* yp = (const float4*)(y + (size_t)row * DIMX);
  float4 a = yp[lane], c = yp[lane + 64];
  float s  = a.x + a.y + a.z + a.w + c.x + c.y + c.z + c.w;
  float ss = a.x*a.x + a.y*a.y + a.z*a.z + a.w*a.w + c.x*c.x + c.y*c.y + c.z*c.z + c.w*c.w;
  #pragma unroll
  for (int m = 1; m < 64; m <<= 1){ s += __shfl_xor(s, m); ss += __shfl_xor(ss, m); }
  float mu = s * (1.f / DIMX);
  float var = ss * (1.f / DIMX) - mu * mu;
  float inv = rsqrtf(var + 1e-5f);
  const float4* gp = (const float4*)gamma;
  const float4* bp = (const float4*)beta;
  float4 g0 = gp[lane], g1 = gp[lane + 64];
  float4 b0 = bp[lane], b1 = bp[lane + 64];
  float4 o0, o1;
  o0.x = (a.x - mu) * inv * g0.x + b0.x; o0.y = (a.y - mu) * inv * g0.y + b0.y;
  o0.z = (a.z - mu) * inv * g0.z + b0.z; o0.w = (a.w - mu) * inv * g0.w + b0.w;
  o1.x = (c.x - mu) * inv * g1.x + b1.x; o1.y = (c.y - mu) * inv * g1.y + b1.y;
  o1.z = (c.z - mu) * inv * g1.z + b1.z; o1.w = (c.w - mu) * inv * g1.w + b1.w;
  float4* op = (float4*)(out + (size_t)row * DIMX);
  op[lane] = o0; op[lane + 64] = o1;
}

extern "C" void kernel_launch(void* const* d_in, const int* in_sizes, int n_in,
                              void* d_out, int out_size, void* d_ws, size_t ws_size,
                              hipStream_t stream){
  const float* x      = (const float*)d_in[0];
  const float* W_qkv  = (const float*)d_in[1];
  const float* b_qkv  = (const float*)d_in[2];
  const float* W_out  = (const float*)d_in[3];
  const float* b_out  = (const float*)d_in[4];
  const float* gamma  = (const float*)d_in[5];
  const float* beta   = (const float*)d_in[6];
  float* out = (float*)d_out;

  char* ws = (char*)d_ws;
  size_t off = 0;
  auto alloc = [&](size_t bytes){ void* p = ws + off; off += (bytes + 255) & ~(size_t)255; return p; };
  unsigned short* xb  = (unsigned short*)alloc((size_t)MTOT * DIMX * 2);
  unsigned short* wqt = (unsigned short*)alloc((size_t)1024 * 512 * 2);
  unsigned short* wot = (unsigned short*)alloc((size_t)512 * 512 * 2);
  unsigned short* qb  = (unsigned short*)alloc((size_t)MTOT * DIMX * 2);
  unsigned short* kb  = (unsigned short*)alloc((size_t)MTOT * DIMX * 2);
  unsigned short* vb  = (unsigned short*)alloc((size_t)MTOT * DIMX * 2);
  unsigned short* vt  = (unsigned short*)alloc((size_t)32 * HDIM * SEQ * 2);
  float*          vsm = (float*)alloc((size_t)32 * HDIM * 4);
  unsigned short* ao  = (unsigned short*)alloc((size_t)MTOT * DIMX * 2);
  float*          yb  = (float*)alloc((size_t)MTOT * DIMX * 4);

  k_cvt <<<(MTOT * DIMX / 8 + 255) / 256, 256, 0, stream>>>(x, xb, MTOT * DIMX / 8);
  k_twt <<<dim3(32, 16), dim3(32, 8), 0, stream>>>(W_qkv, wqt, 512, 1024);
  k_twt <<<dim3(16, 16), dim3(32, 8), 0, stream>>>(W_out, wot, 512, 512);
  k_gemm<<<dim3(32, 8), 256, 0, stream>>>(xb, wqt, b_qkv, 0, qb, kb, vb, nullptr, nullptr);
  k_vt  <<<dim3(8, 32), 256, 0, stream>>>(vb, vt);
  k_vsum<<<32, 256, 0, stream>>>(vb, vsm);
  k_attn<<<dim3(32, 32), 256, 0, stream>>>(qb, kb, vt, vsm, ao);
  k_gemm<<<dim3(32, 4), 256, 0, stream>>>(ao, wot, b_out, 1, qb, kb, vb, x, yb);
  k_ln  <<<MTOT / 4, 256, 0, stream>>>(yb, gamma, beta, out);
}

// Round 2
// 101.467 us; speedup vs baseline: 1.7869x; 1.7869x over previous
//
#include <hip/hip_runtime.h>
#include <cstdint>
#include <cstddef>

#define DIMX 512
#define HDIM 32
#define NHEADS 16
#define SEQ 2048
#define BATCH 2
#define MTOT (BATCH*SEQ)   // 4096
#define WIN 64
#define QSCALE 0.17677669529663687f  // 32^-0.5

typedef __bf16 bf16x8 __attribute__((ext_vector_type(8)));
typedef float f32x4 __attribute__((ext_vector_type(4)));

__device__ __forceinline__ unsigned short f2bf(float f){
  unsigned u = __builtin_bit_cast(unsigned, f);
  u += 0x7FFFu + ((u >> 16) & 1u);          // RNE
  return (unsigned short)(u >> 16);
}
__device__ __forceinline__ float bf2f(unsigned short s){
  return __builtin_bit_cast(float, ((unsigned)s) << 16);
}
__device__ __forceinline__ unsigned pk(float a, float b){
  return (unsigned)f2bf(a) | ((unsigned)f2bf(b) << 16);
}

// ---------- K0: W (K x N fp32) -> Wt (N x K bf16) ----------
__global__ void k_twt(const float* __restrict__ W, unsigned short* __restrict__ Wt, int K, int N){
  __shared__ float tile[32][33];
  int n0 = blockIdx.x * 32, k0 = blockIdx.y * 32;
  int tx = threadIdx.x, ty = threadIdx.y;   // block 32x8
  #pragma unroll
  for (int r = 0; r < 32; r += 8)
    tile[ty + r][tx] = W[(size_t)(k0 + ty + r) * N + n0 + tx];
  __syncthreads();
  #pragma unroll
  for (int r = 0; r < 32; r += 8)
    Wt[(size_t)(n0 + ty + r) * K + k0 + tx] = f2bf(tile[tx][ty + r]);
}

// ---------- K1/K4: bf16 MFMA GEMM, A[M][512] * Bt[N][512]^T ----------
// 128x128 tile, BK=64, 4 waves (2x2 of 64x64), XOR-swizzled LDS.
// MODE 0: A = fp32 x (converted during staging); qkv epilogue
//         (silu*scale -> qb, tanh -> kb, identity -> vb)
// MODE 1: A = bf16 ao; out-proj epilogue: y = acc + bias + xres (fp32)
template<int MODE>
__launch_bounds__(256)
__global__ void k_gemm(const float* __restrict__ Af,
                       const unsigned short* __restrict__ Ab,
                       const unsigned short* __restrict__ Bt,
                       const float* __restrict__ bias,
                       unsigned short* __restrict__ qb,
                       unsigned short* __restrict__ kb,
                       unsigned short* __restrict__ vb,
                       const float* __restrict__ xres,
                       float* __restrict__ y)
{
  const int K = 512;
  __shared__ uint4 As[128 * 8];   // [row][chunk^(row&7)] chunks of 8 bf16
  __shared__ uint4 Bs[128 * 8];
  int tid = threadIdx.x;
  int wid = tid >> 6, lane = tid & 63;
  int wm = wid >> 1, wn = wid & 1;
  int bm = blockIdx.x, bn = blockIdx.y;
  int lane15 = lane & 15, laneh = lane >> 4;

  f32x4 acc[4][4] = {};
  int srow = tid >> 1, shalf = tid & 1;

  for (int kt = 0; kt < K / 64; ++kt){
    int k0 = kt * 64;
    uint4 bv[4];
    const uint4* bp = (const uint4*)(Bt + (size_t)(bn * 128 + srow) * K + k0 + shalf * 32);
    #pragma unroll
    for (int c = 0; c < 4; ++c) bv[c] = bp[c];

    if (MODE == 0){
      float4 f[8];
      const float4* ap = (const float4*)(Af + (size_t)(bm * 128 + srow) * K + k0 + shalf * 32);
      #pragma unroll
      for (int c = 0; c < 8; ++c) f[c] = ap[c];
      __syncthreads();   // previous compute done before overwrite
      #pragma unroll
      for (int c = 0; c < 4; ++c){
        int chunk = shalf * 4 + c;
        uint4 o;
        o.x = pk(f[2*c].x,   f[2*c].y);
        o.y = pk(f[2*c].z,   f[2*c].w);
        o.z = pk(f[2*c+1].x, f[2*c+1].y);
        o.w = pk(f[2*c+1].z, f[2*c+1].w);
        As[srow * 8 + (chunk ^ (srow & 7))] = o;
        Bs[srow * 8 + (chunk ^ (srow & 7))] = bv[c];
      }
    } else {
      uint4 av[4];
      const uint4* ap = (const uint4*)(Ab + (size_t)(bm * 128 + srow) * K + k0 + shalf * 32);
      #pragma unroll
      for (int c = 0; c < 4; ++c) av[c] = ap[c];
      __syncthreads();
      #pragma unroll
      for (int c = 0; c < 4; ++c){
        int chunk = shalf * 4 + c;
        As[srow * 8 + (chunk ^ (srow & 7))] = av[c];
        Bs[srow * 8 + (chunk ^ (srow & 7))] = bv[c];
      }
    }
    __syncthreads();

    #pragma unroll
    for (int kh = 0; kh < 2; ++kh){
      int chunk = kh * 4 + laneh;
      bf16x8 avf[4], bvf[4];
      #pragma unroll
      for (int mi = 0; mi < 4; ++mi){
        int row = wm * 64 + mi * 16 + lane15;
        avf[mi] = *(const bf16x8*)&As[row * 8 + (chunk ^ (row & 7))];
      }
      #pragma unroll
      for (int ni = 0; ni < 4; ++ni){
        int row = wn * 64 + ni * 16 + lane15;
        bvf[ni] = *(const bf16x8*)&Bs[row * 8 + (chunk ^ (row & 7))];
      }
      #pragma unroll
      for (int mi = 0; mi < 4; ++mi)
        #pragma unroll
        for (int ni = 0; ni < 4; ++ni)
          acc[mi][ni] = __builtin_amdgcn_mfma_f32_16x16x32_bf16(avf[mi], bvf[ni], acc[mi][ni], 0, 0, 0);
    }
  }

  #pragma unroll
  for (int mi = 0; mi < 4; ++mi){
    #pragma unroll
    for (int ni = 0; ni < 4; ++ni){
      #pragma unroll
      for (int r = 0; r < 4; ++r){
        int m = bm * 128 + wm * 64 + mi * 16 + laneh * 4 + r;
        int n = bn * 128 + wn * 64 + ni * 16 + lane15;
        float val = acc[mi][ni][r] + bias[n];
        if (MODE == 0){
          if (n < DIMX){
            float s = val / (1.0f + __expf(-val)) * QSCALE;  // silu * scale
            float t = tanhf(val);
            qb[(size_t)m * DIMX + n] = f2bf(s);
            kb[(size_t)m * DIMX + n] = f2bf(t);
          } else {
            vb[(size_t)m * DIMX + (n - DIMX)] = f2bf(val);
          }
        } else {
          size_t idx = (size_t)m * DIMX + n;
          y[idx] = val + xres[idx];
        }
      }
    }
  }
}

// ---------- K2: v [m][512] -> vt [bh*32+d][2048] (bf16) + fused colsum ----------
__global__ void k_vt(const unsigned short* __restrict__ vb, unsigned short* __restrict__ vt,
                     float* __restrict__ vsum){
  __shared__ unsigned short tile[256][34];  // pad to kill bank conflicts
  int sc = blockIdx.x;        // 0..7  (256-row s chunk)
  int bh = blockIdx.y;        // 0..31
  int b = bh >> 4, h = bh & 15;
  int tid = threadIdx.x;
  int d = tid & 31, si = tid >> 5;
  #pragma unroll
  for (int i = 0; i < 32; ++i){
    int sl = i * 8 + si;
    tile[sl][d] = vb[(size_t)(b * SEQ + sc * 256 + sl) * DIMX + h * HDIM + d];
  }
  __syncthreads();
  int wv = tid >> 6, lane = tid & 63;   // wave wv handles dd = ii*4+wv
  #pragma unroll
  for (int ii = 0; ii < 8; ++ii){
    int dd = ii * 4 + wv;
    float acc = 0.f;
    #pragma unroll
    for (int c = 0; c < 4; ++c){
      unsigned short u = tile[c * 64 + lane][dd];
      vt[(size_t)(bh * HDIM + dd) * SEQ + sc * 256 + c * 64 + lane] = u;
      acc += bf2f(u);
    }
    #pragma unroll
    for (int m = 1; m < 64; m <<= 1) acc += __shfl_xor(acc, m);
    if (lane == 0) atomicAdd(&vsum[bh * HDIM + dd], acc);
  }
}

// ---------- K3: banded attention (e^s - 1 trick), MFMA ----------
__launch_bounds__(256)
__global__ void k_attn(const unsigned short* __restrict__ qb,
                       const unsigned short* __restrict__ kb,
                       const unsigned short* __restrict__ vt,
                       const float* __restrict__ vsum,
                       unsigned short* __restrict__ ao)
{
  __shared__ unsigned short p_lds[4][16][40];   // per-wave P staging, padded
  int tid = threadIdx.x, wid = tid >> 6, lane = tid & 63;
  int lane15 = lane & 15, laneh = lane >> 4;
  int bh = blockIdx.y, b = bh >> 4, h = bh & 15;
  int s0 = blockIdx.x * 64 + wid * 16;

  bf16x8 qf = *(const bf16x8*)(qb + (size_t)(b * SEQ + s0 + lane15) * DIMX + h * HDIM + laneh * 8);
  float vs0 = vsum[bh * HDIM + lane15];
  float vs1 = vsum[bh * HDIM + 16 + lane15];

  f32x4 accv[2] = {};
  float dsum[4] = {0.f, 0.f, 0.f, 0.f};

  for (int jt = 0; jt < 10; ++jt){
    int j0 = s0 - 64 + jt * 16;
    int jr = j0 + lane15;
    int jc = min(max(jr, 0), SEQ - 1);
    bf16x8 kf = *(const bf16x8*)(kb + (size_t)(b * SEQ + jc) * DIMX + h * HDIM + laneh * 8);
    f32x4 z = {0.f, 0.f, 0.f, 0.f};
    f32x4 sv = __builtin_amdgcn_mfma_f32_16x16x32_bf16(qf, kf, z, 0, 0, 0);
    #pragma unroll
    for (int r = 0; r < 4; ++r){
      int i = s0 + laneh * 4 + r;
      int j = j0 + lane15;
      int dj = i - j;
      bool inb = (dj <= WIN) && (dj >= -WIN) && (j >= 0) && (j < SEQ);
      float w = inb ? (__expf(sv[r]) - 1.0f) : 0.0f;
      dsum[r] += w;
      p_lds[wid][laneh * 4 + r][(jt & 1) * 16 + lane15] = f2bf(w);
    }
    if (jt & 1){
      int jc0 = j0 - 16;   // 32-wide chunk base
      bf16x8 pa = *(const bf16x8*)&p_lds[wid][lane15][laneh * 8];
      int jv = min(max(jc0 + laneh * 8, 0), SEQ - 8);
      bf16x8 v0 = *(const bf16x8*)(vt + (size_t)(bh * HDIM + lane15) * SEQ + jv);
      bf16x8 v1 = *(const bf16x8*)(vt + (size_t)(bh * HDIM + 16 + lane15) * SEQ + jv);
      accv[0] = __builtin_amdgcn_mfma_f32_16x16x32_bf16(pa, v0, accv[0], 0, 0, 0);
      accv[1] = __builtin_amdgcn_mfma_f32_16x16x32_bf16(pa, v1, accv[1], 0, 0, 0);
    }
  }

  #pragma unroll
  for (int r = 0; r < 4; ++r){
    float v = dsum[r];
    v += __shfl_xor(v, 1); v += __shfl_xor(v, 2);
    v += __shfl_xor(v, 4); v += __shfl_xor(v, 8);
    dsum[r] = v;
  }
  #pragma unroll
  for (int r = 0; r < 4; ++r){
    int i = s0 + laneh * 4 + r;
    float dn = (float)SEQ + dsum[r];
    float o0 = (accv[0][r] + vs0) / dn;
    float o1 = (accv[1][r] + vs1) / dn;
    size_t base = (size_t)(b * SEQ + i) * DIMX + h * HDIM;
    ao[base + lane15]      = f2bf(o0);
    ao[base + 16 + lane15] = f2bf(o1);
  }
}

// ---------- K5: LayerNorm over 512, one wave per row ----------
__global__ void k_ln(const float* __restrict__ y, const float* __restrict__ gamma,
                     const float* __restrict__ beta, float* __restrict__ out){
  int wid = threadIdx.x >> 6, lane = threadIdx.x & 63;
  int row = blockIdx.x * 4 + wid;
  const float4* yp = (const float4*)(y + (size_t)row * DIMX);
  float4 a = yp[lane], c = yp[lane + 64];
  float s  = a.x + a.y + a.z + a.w + c.x + c.y + c.z + c.w;
  float ss = a.x*a.x + a.y*a.y + a.z*a.z + a.w*a.w + c.x*c.x + c.y*c.y + c.z*c.z + c.w*c.w;
  #pragma unroll
  for (int m = 1; m < 64; m <<= 1){ s += __shfl_xor(s, m); ss += __shfl_xor(ss, m); }
  float mu = s * (1.f / DIMX);
  float var = ss * (1.f / DIMX) - mu * mu;
  float inv = rsqrtf(var + 1e-5f);
  const float4* gp = (const float4*)gamma;
  const float4* bp = (const float4*)beta;
  float4 g0 = gp[lane], g1 = gp[lane + 64];
  float4 b0 = bp[lane], b1 = bp[lane + 64];
  float4 o0, o1;
  o0.x = (a.x - mu) * inv * g0.x + b0.x; o0.y = (a.y - mu) * inv * g0.y + b0.y;
  o0.z = (a.z - mu) * inv * g0.z + b0.z; o0.w = (a.w - mu) * inv * g0.w + b0.w;
  o1.x = (c.x - mu) * inv * g1.x + b1.x; o1.y = (c.y - mu) * inv * g1.y + b1.y;
  o1.z = (c.z - mu) * inv * g1.z + b1.z; o1.w = (c.w - mu) * inv * g1.w + b1.w;
  float4* op = (float4*)(out + (size_t)row * DIMX);
  op[lane] = o0; op[lane + 64] = o1;
}

extern "C" void kernel_launch(void* const* d_in, const int* in_sizes, int n_in,
                              void* d_out, int out_size, void* d_ws, size_t ws_size,
                              hipStream_t stream){
  const float* x      = (const float*)d_in[0];
  const float* W_qkv  = (const float*)d_in[1];
  const float* b_qkv  = (const float*)d_in[2];
  const float* W_out  = (const float*)d_in[3];
  const float* b_out  = (const float*)d_in[4];
  const float* gamma  = (const float*)d_in[5];
  const float* beta   = (const float*)d_in[6];
  float* out = (float*)d_out;

  char* ws = (char*)d_ws;
  size_t off = 0;
  auto alloc = [&](size_t bytes){ void* p = ws + off; off += (bytes + 255) & ~(size_t)255; return p; };
  unsigned short* wqt = (unsigned short*)alloc((size_t)1024 * 512 * 2);
  unsigned short* wot = (unsigned short*)alloc((size_t)512 * 512 * 2);
  unsigned short* qb  = (unsigned short*)alloc((size_t)MTOT * DIMX * 2);
  unsigned short* kb  = (unsigned short*)alloc((size_t)MTOT * DIMX * 2);
  unsigned short* vb  = (unsigned short*)alloc((size_t)MTOT * DIMX * 2);
  unsigned short* vt  = (unsigned short*)alloc((size_t)32 * HDIM * SEQ * 2);
  float*          vsm = (float*)alloc((size_t)32 * HDIM * 4);
  unsigned short* ao  = (unsigned short*)alloc((size_t)MTOT * DIMX * 2);
  float*          yb  = (float*)alloc((size_t)MTOT * DIMX * 4);

  hipMemsetAsync(vsm, 0, (size_t)32 * HDIM * 4, stream);
  k_twt <<<dim3(32, 16), dim3(32, 8), 0, stream>>>(W_qkv, wqt, 512, 1024);
  k_twt <<<dim3(16, 16), dim3(32, 8), 0, stream>>>(W_out, wot, 512, 512);
  k_gemm<0><<<dim3(32, 8), 256, 0, stream>>>(x, nullptr, wqt, b_qkv, qb, kb, vb, nullptr, nullptr);
  k_vt  <<<dim3(8, 32), 256, 0, stream>>>(vb, vt, vsm);
  k_attn<<<dim3(32, 32), 256, 0, stream>>>(qb, kb, vt, vsm, ao);
  k_gemm<1><<<dim3(32, 4), 256, 0, stream>>>(nullptr, ao, wot, b_out, qb, kb, vb, x, yb);
  k_ln  <<<MTOT / 4, 256, 0, stream>>>(yb, gamma, beta, out);
}

// Round 3
// 98.578 us; speedup vs baseline: 1.8393x; 1.0293x over previous
//
#include <hip/hip_runtime.h>
#include <cstdint>
#include <cstddef>

#define DIMX 512
#define HDIM 32
#define NHEADS 16
#define SEQ 2048
#define BATCH 2
#define MTOT (BATCH*SEQ)   // 4096
#define WIN 64
#define QSCALE 0.17677669529663687f  // 32^-0.5

typedef __bf16 bf16x8 __attribute__((ext_vector_type(8)));
typedef float f32x4 __attribute__((ext_vector_type(4)));

__device__ __forceinline__ unsigned short f2bf(float f){
  unsigned u = __builtin_bit_cast(unsigned, f);
  u += 0x7FFFu + ((u >> 16) & 1u);          // RNE
  return (unsigned short)(u >> 16);
}
__device__ __forceinline__ float bf2f(unsigned short s){
  return __builtin_bit_cast(float, ((unsigned)s) << 16);
}
__device__ __forceinline__ unsigned pk(float a, float b){
  return (unsigned)f2bf(a) | ((unsigned)f2bf(b) << 16);
}

// ---------- K0: W (K x N fp32) -> Wt (N x K bf16) ----------
__global__ void k_twt(const float* __restrict__ W, unsigned short* __restrict__ Wt, int K, int N){
  __shared__ float tile[32][33];
  int n0 = blockIdx.x * 32, k0 = blockIdx.y * 32;
  int tx = threadIdx.x, ty = threadIdx.y;   // block 32x8
  #pragma unroll
  for (int r = 0; r < 32; r += 8)
    tile[ty + r][tx] = W[(size_t)(k0 + ty + r) * N + n0 + tx];
  __syncthreads();
  #pragma unroll
  for (int r = 0; r < 32; r += 8)
    Wt[(size_t)(n0 + ty + r) * K + k0 + tx] = f2bf(tile[tx][ty + r]);
}

// ---------- K1/K4: bf16 MFMA GEMM, A[M][512] * Bt[N][512]^T ----------
// 128x128 tile, BK=64, 4 waves (2x2 of 64x64), XOR-swizzled LDS.
// MODE 0: A = fp32 x (converted during staging); qkv epilogue
//         (silu*scale -> qb, tanh -> kb, identity -> vb)
// MODE 1: A = bf16 ao; out-proj epilogue: y = acc + bias + xres (fp32)
template<int MODE>
__launch_bounds__(256)
__global__ void k_gemm(const float* __restrict__ Af,
                       const unsigned short* __restrict__ Ab,
                       const unsigned short* __restrict__ Bt,
                       const float* __restrict__ bias,
                       unsigned short* __restrict__ qb,
                       unsigned short* __restrict__ kb,
                       unsigned short* __restrict__ vb,
                       const float* __restrict__ xres,
                       float* __restrict__ y)
{
  const int K = 512;
  __shared__ uint4 As[128 * 8];   // [row][chunk^(row&7)] chunks of 8 bf16
  __shared__ uint4 Bs[128 * 8];
  int tid = threadIdx.x;
  int wid = tid >> 6, lane = tid & 63;
  int wm = wid >> 1, wn = wid & 1;
  int bm = blockIdx.x, bn = blockIdx.y;
  int lane15 = lane & 15, laneh = lane >> 4;

  f32x4 acc[4][4] = {};
  int srow = tid >> 1, shalf = tid & 1;

  for (int kt = 0; kt < K / 64; ++kt){
    int k0 = kt * 64;
    uint4 bv[4];
    const uint4* bp = (const uint4*)(Bt + (size_t)(bn * 128 + srow) * K + k0 + shalf * 32);
    #pragma unroll
    for (int c = 0; c < 4; ++c) bv[c] = bp[c];

    if (MODE == 0){
      float4 f[8];
      const float4* ap = (const float4*)(Af + (size_t)(bm * 128 + srow) * K + k0 + shalf * 32);
      #pragma unroll
      for (int c = 0; c < 8; ++c) f[c] = ap[c];
      __syncthreads();   // previous compute done before overwrite
      #pragma unroll
      for (int c = 0; c < 4; ++c){
        int chunk = shalf * 4 + c;
        uint4 o;
        o.x = pk(f[2*c].x,   f[2*c].y);
        o.y = pk(f[2*c].z,   f[2*c].w);
        o.z = pk(f[2*c+1].x, f[2*c+1].y);
        o.w = pk(f[2*c+1].z, f[2*c+1].w);
        As[srow * 8 + (chunk ^ (srow & 7))] = o;
        Bs[srow * 8 + (chunk ^ (srow & 7))] = bv[c];
      }
    } else {
      uint4 av[4];
      const uint4* ap = (const uint4*)(Ab + (size_t)(bm * 128 + srow) * K + k0 + shalf * 32);
      #pragma unroll
      for (int c = 0; c < 4; ++c) av[c] = ap[c];
      __syncthreads();
      #pragma unroll
      for (int c = 0; c < 4; ++c){
        int chunk = shalf * 4 + c;
        As[srow * 8 + (chunk ^ (srow & 7))] = av[c];
        Bs[srow * 8 + (chunk ^ (srow & 7))] = bv[c];
      }
    }
    __syncthreads();

    #pragma unroll
    for (int kh = 0; kh < 2; ++kh){
      int chunk = kh * 4 + laneh;
      bf16x8 avf[4], bvf[4];
      #pragma unroll
      for (int mi = 0; mi < 4; ++mi){
        int row = wm * 64 + mi * 16 + lane15;
        avf[mi] = *(const bf16x8*)&As[row * 8 + (chunk ^ (row & 7))];
      }
      #pragma unroll
      for (int ni = 0; ni < 4; ++ni){
        int row = wn * 64 + ni * 16 + lane15;
        bvf[ni] = *(const bf16x8*)&Bs[row * 8 + (chunk ^ (row & 7))];
      }
      #pragma unroll
      for (int mi = 0; mi < 4; ++mi)
        #pragma unroll
        for (int ni = 0; ni < 4; ++ni)
          acc[mi][ni] = __builtin_amdgcn_mfma_f32_16x16x32_bf16(avf[mi], bvf[ni], acc[mi][ni], 0, 0, 0);
    }
  }

  #pragma unroll
  for (int mi = 0; mi < 4; ++mi){
    #pragma unroll
    for (int ni = 0; ni < 4; ++ni){
      #pragma unroll
      for (int r = 0; r < 4; ++r){
        int m = bm * 128 + wm * 64 + mi * 16 + laneh * 4 + r;
        int n = bn * 128 + wn * 64 + ni * 16 + lane15;
        float val = acc[mi][ni][r] + bias[n];
        if (MODE == 0){
          if (n < DIMX){
            float s = val / (1.0f + __expf(-val)) * QSCALE;  // silu * scale
            float t = tanhf(val);
            qb[(size_t)m * DIMX + n] = f2bf(s);
            kb[(size_t)m * DIMX + n] = f2bf(t);
          } else {
            vb[(size_t)m * DIMX + (n - DIMX)] = f2bf(val);
          }
        } else {
          size_t idx = (size_t)m * DIMX + n;
          y[idx] = val + xres[idx];
        }
      }
    }
  }
}

// ---------- K2: v [m][512] -> vt [bh*32+d][2048] (bf16) + partial colsums ----------
// vsum_p layout: [8 s-chunks][32 bh][32 d] fp32 — every slot written every call,
// no init / no atomics needed (memset inside the graph cost ~40 us!).
__global__ void k_vt(const unsigned short* __restrict__ vb, unsigned short* __restrict__ vt,
                     float* __restrict__ vsum_p){
  __shared__ unsigned short tile[256][34];  // pad to kill bank conflicts
  int sc = blockIdx.x;        // 0..7  (256-row s chunk)
  int bh = blockIdx.y;        // 0..31
  int b = bh >> 4, h = bh & 15;
  int tid = threadIdx.x;
  int d = tid & 31, si = tid >> 5;
  #pragma unroll
  for (int i = 0; i < 32; ++i){
    int sl = i * 8 + si;
    tile[sl][d] = vb[(size_t)(b * SEQ + sc * 256 + sl) * DIMX + h * HDIM + d];
  }
  __syncthreads();
  int wv = tid >> 6, lane = tid & 63;   // wave wv handles dd = ii*4+wv
  #pragma unroll
  for (int ii = 0; ii < 8; ++ii){
    int dd = ii * 4 + wv;
    float acc = 0.f;
    #pragma unroll
    for (int c = 0; c < 4; ++c){
      unsigned short u = tile[c * 64 + lane][dd];
      vt[(size_t)(bh * HDIM + dd) * SEQ + sc * 256 + c * 64 + lane] = u;
      acc += bf2f(u);
    }
    #pragma unroll
    for (int m = 1; m < 64; m <<= 1) acc += __shfl_xor(acc, m);
    if (lane == 0) vsum_p[(sc * 32 + bh) * HDIM + dd] = acc;
  }
}

// ---------- K3: banded attention (e^s - 1 trick), MFMA ----------
__launch_bounds__(256)
__global__ void k_attn(const unsigned short* __restrict__ qb,
                       const unsigned short* __restrict__ kb,
                       const unsigned short* __restrict__ vt,
                       const float* __restrict__ vsum_p,
                       unsigned short* __restrict__ ao)
{
  __shared__ unsigned short p_lds[4][16][40];   // per-wave P staging, padded
  int tid = threadIdx.x, wid = tid >> 6, lane = tid & 63;
  int lane15 = lane & 15, laneh = lane >> 4;
  int bh = blockIdx.y, b = bh >> 4, h = bh & 15;
  int s0 = blockIdx.x * 64 + wid * 16;

  bf16x8 qf = *(const bf16x8*)(qb + (size_t)(b * SEQ + s0 + lane15) * DIMX + h * HDIM + laneh * 8);
  float vs0 = 0.f, vs1 = 0.f;
  #pragma unroll
  for (int c = 0; c < 8; ++c){
    vs0 += vsum_p[(c * 32 + bh) * HDIM + lane15];
    vs1 += vsum_p[(c * 32 + bh) * HDIM + 16 + lane15];
  }

  f32x4 accv[2] = {};
  float dsum[4] = {0.f, 0.f, 0.f, 0.f};

  for (int jt = 0; jt < 10; ++jt){
    int j0 = s0 - 64 + jt * 16;
    int jr = j0 + lane15;
    int jc = min(max(jr, 0), SEQ - 1);
    bf16x8 kf = *(const bf16x8*)(kb + (size_t)(b * SEQ + jc) * DIMX + h * HDIM + laneh * 8);
    f32x4 z = {0.f, 0.f, 0.f, 0.f};
    f32x4 sv = __builtin_amdgcn_mfma_f32_16x16x32_bf16(qf, kf, z, 0, 0, 0);
    #pragma unroll
    for (int r = 0; r < 4; ++r){
      int i = s0 + laneh * 4 + r;
      int j = j0 + lane15;
      int dj = i - j;
      bool inb = (dj <= WIN) && (dj >= -WIN) && (j >= 0) && (j < SEQ);
      float w = inb ? (__expf(sv[r]) - 1.0f) : 0.0f;
      dsum[r] += w;
      p_lds[wid][laneh * 4 + r][(jt & 1) * 16 + lane15] = f2bf(w);
    }
    if (jt & 1){
      int jc0 = j0 - 16;   // 32-wide chunk base
      bf16x8 pa = *(const bf16x8*)&p_lds[wid][lane15][laneh * 8];
      int jv = min(max(jc0 + laneh * 8, 0), SEQ - 8);
      bf16x8 v0 = *(const bf16x8*)(vt + (size_t)(bh * HDIM + lane15) * SEQ + jv);
      bf16x8 v1 = *(const bf16x8*)(vt + (size_t)(bh * HDIM + 16 + lane15) * SEQ + jv);
      accv[0] = __builtin_amdgcn_mfma_f32_16x16x32_bf16(pa, v0, accv[0], 0, 0, 0);
      accv[1] = __builtin_amdgcn_mfma_f32_16x16x32_bf16(pa, v1, accv[1], 0, 0, 0);
    }
  }

  #pragma unroll
  for (int r = 0; r < 4; ++r){
    float v = dsum[r];
    v += __shfl_xor(v, 1); v += __shfl_xor(v, 2);
    v += __shfl_xor(v, 4); v += __shfl_xor(v, 8);
    dsum[r] = v;
  }
  #pragma unroll
  for (int r = 0; r < 4; ++r){
    int i = s0 + laneh * 4 + r;
    float dn = (float)SEQ + dsum[r];
    float o0 = (accv[0][r] + vs0) / dn;
    float o1 = (accv[1][r] + vs1) / dn;
    size_t base = (size_t)(b * SEQ + i) * DIMX + h * HDIM;
    ao[base + lane15]      = f2bf(o0);
    ao[base + 16 + lane15] = f2bf(o1);
  }
}

// ---------- K5: LayerNorm over 512, one wave per row ----------
__global__ void k_ln(const float* __restrict__ y, const float* __restrict__ gamma,
                     const float* __restrict__ beta, float* __restrict__ out){
  int wid = threadIdx.x >> 6, lane = threadIdx.x & 63;
  int row = blockIdx.x * 4 + wid;
  const float4* yp = (const float4*)(y + (size_t)row * DIMX);
  float4 a = yp[lane], c = yp[lane + 64];
  float s  = a.x + a.y + a.z + a.w + c.x + c.y + c.z + c.w;
  float ss = a.x*a.x + a.y*a.y + a.z*a.z + a.w*a.w + c.x*c.x + c.y*c.y + c.z*c.z + c.w*c.w;
  #pragma unroll
  for (int m = 1; m < 64; m <<= 1){ s += __shfl_xor(s, m); ss += __shfl_xor(ss, m); }
  float mu = s * (1.f / DIMX);
  float var = ss * (1.f / DIMX) - mu * mu;
  float inv = rsqrtf(var + 1e-5f);
  const float4* gp = (const float4*)gamma;
  const float4* bp = (const float4*)beta;
  float4 g0 = gp[lane], g1 = gp[lane + 64];
  float4 b0 = bp[lane], b1 = bp[lane + 64];
  float4 o0, o1;
  o0.x = (a.x - mu) * inv * g0.x + b0.x; o0.y = (a.y - mu) * inv * g0.y + b0.y;
  o0.z = (a.z - mu) * inv * g0.z + b0.z; o0.w = (a.w - mu) * inv * g0.w + b0.w;
  o1.x = (c.x - mu) * inv * g1.x + b1.x; o1.y = (c.y - mu) * inv * g1.y + b1.y;
  o1.z = (c.z - mu) * inv * g1.z + b1.z; o1.w = (c.w - mu) * inv * g1.w + b1.w;
  float4* op = (float4*)(out + (size_t)row * DIMX);
  op[lane] = o0; op[lane + 64] = o1;
}

extern "C" void kernel_launch(void* const* d_in, const int* in_sizes, int n_in,
                              void* d_out, int out_size, void* d_ws, size_t ws_size,
                              hipStream_t stream){
  const float* x      = (const float*)d_in[0];
  const float* W_qkv  = (const float*)d_in[1];
  const float* b_qkv  = (const float*)d_in[2];
  const float* W_out  = (const float*)d_in[3];
  const float* b_out  = (const float*)d_in[4];
  const float* gamma  = (const float*)d_in[5];
  const float* beta   = (const float*)d_in[6];
  float* out = (float*)d_out;

  char* ws = (char*)d_ws;
  size_t off = 0;
  auto alloc = [&](size_t bytes){ void* p = ws + off; off += (bytes + 255) & ~(size_t)255; return p; };
  unsigned short* wqt = (unsigned short*)alloc((size_t)1024 * 512 * 2);
  unsigned short* wot = (unsigned short*)alloc((size_t)512 * 512 * 2);
  unsigned short* qb  = (unsigned short*)alloc((size_t)MTOT * DIMX * 2);
  unsigned short* kb  = (unsigned short*)alloc((size_t)MTOT * DIMX * 2);
  unsigned short* vb  = (unsigned short*)alloc((size_t)MTOT * DIMX * 2);
  unsigned short* vt  = (unsigned short*)alloc((size_t)32 * HDIM * SEQ * 2);
  float*          vsm = (float*)alloc((size_t)8 * 32 * HDIM * 4);
  unsigned short* ao  = (unsigned short*)alloc((size_t)MTOT * DIMX * 2);
  float*          yb  = (float*)alloc((size_t)MTOT * DIMX * 4);

  k_twt <<<dim3(32, 16), dim3(32, 8), 0, stream>>>(W_qkv, wqt, 512, 1024);
  k_twt <<<dim3(16, 16), dim3(32, 8), 0, stream>>>(W_out, wot, 512, 512);
  k_gemm<0><<<dim3(32, 8), 256, 0, stream>>>(x, nullptr, wqt, b_qkv, qb, kb, vb, nullptr, nullptr);
  k_vt  <<<dim3(8, 32), 256, 0, stream>>>(vb, vt, vsm);
  k_attn<<<dim3(32, 32), 256, 0, stream>>>(qb, kb, vt, vsm, ao);
  k_gemm<1><<<dim3(32, 4), 256, 0, stream>>>(nullptr, ao, wot, b_out, qb, kb, vb, x, yb);
  k_ln  <<<MTOT / 4, 256, 0, stream>>>(yb, gamma, beta, out);
}

// Round 4
// 96.620 us; speedup vs baseline: 1.8765x; 1.0203x over previous
//
#include <hip/hip_runtime.h>
#include <cstdint>
#include <cstddef>

#define DIMX 512
#define HDIM 32
#define NHEADS 16
#define SEQ 2048
#define BATCH 2
#define MTOT (BATCH*SEQ)   // 4096
#define WIN 64
#define QSCALE 0.17677669529663687f  // 32^-0.5

typedef __bf16 bf16x8 __attribute__((ext_vector_type(8)));
typedef float f32x4 __attribute__((ext_vector_type(4)));

__device__ __forceinline__ unsigned short f2bf(float f){
  unsigned u = __builtin_bit_cast(unsigned, f);
  u += 0x7FFFu + ((u >> 16) & 1u);          // RNE
  return (unsigned short)(u >> 16);
}
__device__ __forceinline__ float bf2f(unsigned short s){
  return __builtin_bit_cast(float, ((unsigned)s) << 16);
}
__device__ __forceinline__ unsigned pk(float a, float b){
  return (unsigned)f2bf(a) | ((unsigned)f2bf(b) << 16);
}

// ---------- K0a: fp32 -> bf16, 8 elems/thread ----------
__global__ void k_cvt(const float* __restrict__ src, unsigned short* __restrict__ dst, int n8){
  int i = blockIdx.x * blockDim.x + threadIdx.x;
  if (i >= n8) return;
  const float4* p = (const float4*)src + (size_t)i * 2;
  float4 a = p[0], b = p[1];
  uint4 o;
  o.x = pk(a.x, a.y); o.y = pk(a.z, a.w);
  o.z = pk(b.x, b.y); o.w = pk(b.z, b.w);
  ((uint4*)dst)[i] = o;
}

// ---------- K0b: both weight transposes in one launch ----------
// x-block < 32: W_qkv (512x1024) -> wqt (1024x512); else W_out (512x512) -> wot
__global__ void k_twt(const float* __restrict__ Wq, unsigned short* __restrict__ Wqt,
                      const float* __restrict__ Wo, unsigned short* __restrict__ Wot){
  __shared__ float tile[32][33];
  int bx = blockIdx.x;
  const float* W; unsigned short* Wt; int N, n0;
  if (bx < 32){ W = Wq; Wt = Wqt; N = 1024; n0 = bx * 32; }
  else        { W = Wo; Wt = Wot; N = 512;  n0 = (bx - 32) * 32; }
  int k0 = blockIdx.y * 32;
  int tx = threadIdx.x, ty = threadIdx.y;   // block 32x8
  #pragma unroll
  for (int r = 0; r < 32; r += 8)
    tile[ty + r][tx] = W[(size_t)(k0 + ty + r) * N + n0 + tx];
  __syncthreads();
  #pragma unroll
  for (int r = 0; r < 32; r += 8)
    Wt[(size_t)(n0 + ty + r) * 512 + k0 + tx] = f2bf(tile[tx][ty + r]);
}

// ---------- K1/K4: bf16 MFMA GEMM, A[M][512] * Bt[N][512]^T ----------
// BM x 128 tile, BK=64, 4 waves (2x2 of BM/2 x 64), XOR-swizzled LDS,
// bijective XCD block swizzle (nwg = 512, %8 == 0).
// MODE 0: qkv epilogue (silu*scale -> qb, tanh -> kb, identity -> vb)
// MODE 1: out-proj epilogue: y = acc + bias + xres (fp32)
template<int MODE, int BM, int NBN>
__launch_bounds__(256)
__global__ void k_gemm(const unsigned short* __restrict__ A,
                       const unsigned short* __restrict__ Bt,
                       const float* __restrict__ bias,
                       unsigned short* __restrict__ qb,
                       unsigned short* __restrict__ kb,
                       unsigned short* __restrict__ vb,
                       const float* __restrict__ xres,
                       float* __restrict__ y)
{
  const int K = 512;
  constexpr int MF = BM / 32;            // m-fragments per wave
  constexpr int NWG = (MTOT / BM) * NBN; // total workgroups (512)
  __shared__ uint4 As[BM * 8];   // [row][chunk^(row&7)], chunk = 8 bf16 (16B)
  __shared__ uint4 Bs[128 * 8];
  int tid = threadIdx.x;
  int wid = tid >> 6, lane = tid & 63;
  int wm = wid >> 1, wn = wid & 1;
  int lane15 = lane & 15, laneh = lane >> 4;

  // XCD-aware bijective swizzle: same-bm blocks land on the same XCD L2
  int g = blockIdx.y * gridDim.x + blockIdx.x;
  int gwi = (g & 7) * (NWG / 8) + (g >> 3);
  int bm = gwi / NBN, bn = gwi % NBN;

  f32x4 acc[MF][4] = {};

  constexpr int ACH = BM * 8 / 256;       // A chunks per thread (2 or 1)
  constexpr int TPR = 256 / BM;           // threads per A row (4 or 8)
  int arow = tid / TPR, ach0 = (tid % TPR) * ACH;
  int brow = tid >> 1, bch0 = (tid & 1) * 4;

  for (int kt = 0; kt < K / 64; ++kt){
    int k0 = kt * 64;
    uint4 av[ACH], bv[4];
    const uint4* ap = (const uint4*)(A  + (size_t)(bm * BM  + arow) * K + k0 + ach0 * 8);
    const uint4* bp = (const uint4*)(Bt + (size_t)(bn * 128 + brow) * K + k0 + bch0 * 8);
    #pragma unroll
    for (int c = 0; c < ACH; ++c) av[c] = ap[c];
    #pragma unroll
    for (int c = 0; c < 4; ++c)   bv[c] = bp[c];
    __syncthreads();   // previous compute done before overwrite
    #pragma unroll
    for (int c = 0; c < ACH; ++c)
      As[arow * 8 + ((ach0 + c) ^ (arow & 7))] = av[c];
    #pragma unroll
    for (int c = 0; c < 4; ++c)
      Bs[brow * 8 + ((bch0 + c) ^ (brow & 7))] = bv[c];
    __syncthreads();

    #pragma unroll
    for (int kh = 0; kh < 2; ++kh){
      int chunk = kh * 4 + laneh;
      bf16x8 avf[MF], bvf[4];
      #pragma unroll
      for (int mi = 0; mi < MF; ++mi){
        int row = wm * (BM / 2) + mi * 16 + lane15;
        avf[mi] = *(const bf16x8*)&As[row * 8 + (chunk ^ (row & 7))];
      }
      #pragma unroll
      for (int ni = 0; ni < 4; ++ni){
        int row = wn * 64 + ni * 16 + lane15;
        bvf[ni] = *(const bf16x8*)&Bs[row * 8 + (chunk ^ (row & 7))];
      }
      #pragma unroll
      for (int mi = 0; mi < MF; ++mi)
        #pragma unroll
        for (int ni = 0; ni < 4; ++ni)
          acc[mi][ni] = __builtin_amdgcn_mfma_f32_16x16x32_bf16(avf[mi], bvf[ni], acc[mi][ni], 0, 0, 0);
    }
  }

  #pragma unroll
  for (int mi = 0; mi < MF; ++mi){
    #pragma unroll
    for (int ni = 0; ni < 4; ++ni){
      #pragma unroll
      for (int r = 0; r < 4; ++r){
        int m = bm * BM + wm * (BM / 2) + mi * 16 + laneh * 4 + r;
        int n = bn * 128 + wn * 64 + ni * 16 + lane15;
        float val = acc[mi][ni][r] + bias[n];
        if (MODE == 0){
          if (n < DIMX){
            float s = val / (1.0f + __expf(-val)) * QSCALE;  // silu * scale
            float t = tanhf(val);
            qb[(size_t)m * DIMX + n] = f2bf(s);
            kb[(size_t)m * DIMX + n] = f2bf(t);
          } else {
            vb[(size_t)m * DIMX + (n - DIMX)] = f2bf(val);
          }
        } else {
          size_t idx = (size_t)m * DIMX + n;
          y[idx] = val + xres[idx];
        }
      }
    }
  }
}

// ---------- K2: v [m][512] -> vt [bh*32+d][2048] (bf16) + partial colsums ----------
// vsum_p layout: [8 s-chunks][32 bh][32 d] fp32 — every slot written every call,
// no init / no atomics needed.
__global__ void k_vt(const unsigned short* __restrict__ vb, unsigned short* __restrict__ vt,
                     float* __restrict__ vsum_p){
  __shared__ unsigned short tile[256][34];  // pad to kill bank conflicts
  int sc = blockIdx.x;        // 0..7  (256-row s chunk)
  int bh = blockIdx.y;        // 0..31
  int b = bh >> 4, h = bh & 15;
  int tid = threadIdx.x;
  int d = tid & 31, si = tid >> 5;
  #pragma unroll
  for (int i = 0; i < 32; ++i){
    int sl = i * 8 + si;
    tile[sl][d] = vb[(size_t)(b * SEQ + sc * 256 + sl) * DIMX + h * HDIM + d];
  }
  __syncthreads();
  int wv = tid >> 6, lane = tid & 63;   // wave wv handles dd = ii*4+wv
  #pragma unroll
  for (int ii = 0; ii < 8; ++ii){
    int dd = ii * 4 + wv;
    float acc = 0.f;
    #pragma unroll
    for (int c = 0; c < 4; ++c){
      unsigned short u = tile[c * 64 + lane][dd];
      vt[(size_t)(bh * HDIM + dd) * SEQ + sc * 256 + c * 64 + lane] = u;
      acc += bf2f(u);
    }
    #pragma unroll
    for (int m = 1; m < 64; m <<= 1) acc += __shfl_xor(acc, m);
    if (lane == 0) vsum_p[(sc * 32 + bh) * HDIM + dd] = acc;
  }
}

// ---------- K3: banded attention (e^s - 1 trick), MFMA, 9 k-tiles ----------
__launch_bounds__(256)
__global__ void k_attn(const unsigned short* __restrict__ qb,
                       const unsigned short* __restrict__ kb,
                       const unsigned short* __restrict__ vt,
                       const float* __restrict__ vsum_p,
                       unsigned short* __restrict__ ao)
{
  __shared__ unsigned short p_lds[4][16][40];   // per-wave P staging, padded
  int tid = threadIdx.x, wid = tid >> 6, lane = tid & 63;
  int lane15 = lane & 15, laneh = lane >> 4;
  int bh = blockIdx.y, b = bh >> 4, h = bh & 15;
  int s0 = blockIdx.x * 64 + wid * 16;

  bf16x8 qf = *(const bf16x8*)(qb + (size_t)(b * SEQ + s0 + lane15) * DIMX + h * HDIM + laneh * 8);
  float vs0 = 0.f, vs1 = 0.f;
  #pragma unroll
  for (int c = 0; c < 8; ++c){
    vs0 += vsum_p[(c * 32 + bh) * HDIM + lane15];
    vs1 += vsum_p[(c * 32 + bh) * HDIM + 16 + lane15];
  }

  f32x4 accv[2] = {};
  float dsum[4] = {0.f, 0.f, 0.f, 0.f};

  // band |i-j|<=64 with i in [s0, s0+16) touches j in [s0-64, s0+80) = 9 tiles
  for (int jt = 0; jt < 9; ++jt){
    int j0 = s0 - 64 + jt * 16;
    int jc = min(max(j0 + lane15, 0), SEQ - 1);
    bf16x8 kf = *(const bf16x8*)(kb + (size_t)(b * SEQ + jc) * DIMX + h * HDIM + laneh * 8);
    f32x4 z = {0.f, 0.f, 0.f, 0.f};
    f32x4 sv = __builtin_amdgcn_mfma_f32_16x16x32_bf16(qf, kf, z, 0, 0, 0);
    #pragma unroll
    for (int r = 0; r < 4; ++r){
      int i = s0 + laneh * 4 + r;
      int j = j0 + lane15;
      int dj = i - j;
      bool inb = (dj <= WIN) && (dj >= -WIN) && (j >= 0) && (j < SEQ);
      float w = inb ? (__expf(sv[r]) - 1.0f) : 0.0f;
      dsum[r] += w;
      p_lds[wid][laneh * 4 + r][(jt & 1) * 16 + lane15] = f2bf(w);
    }
    if (jt & 1){
      int jc0 = j0 - 16;   // 32-wide chunk base
      bf16x8 pa = *(const bf16x8*)&p_lds[wid][lane15][laneh * 8];
      int jv = min(max(jc0 + laneh * 8, 0), SEQ - 8);
      bf16x8 v0 = *(const bf16x8*)(vt + (size_t)(bh * HDIM + lane15) * SEQ + jv);
      bf16x8 v1 = *(const bf16x8*)(vt + (size_t)(bh * HDIM + 16 + lane15) * SEQ + jv);
      accv[0] = __builtin_amdgcn_mfma_f32_16x16x32_bf16(pa, v0, accv[0], 0, 0, 0);
      accv[1] = __builtin_amdgcn_mfma_f32_16x16x32_bf16(pa, v1, accv[1], 0, 0, 0);
    }
  }
  // tail PV for tile 8 (sitting in cols 0..15); zero cols 16..31 first
  {
    #pragma unroll
    for (int r = 0; r < 4; ++r)
      p_lds[wid][laneh * 4 + r][16 + lane15] = 0;
    int jc0 = s0 + 64;
    bf16x8 pa = *(const bf16x8*)&p_lds[wid][lane15][laneh * 8];
    int jv = min(max(jc0 + laneh * 8, 0), SEQ - 8);
    bf16x8 v0 = *(const bf16x8*)(vt + (size_t)(bh * HDIM + lane15) * SEQ + jv);
    bf16x8 v1 = *(const bf16x8*)(vt + (size_t)(bh * HDIM + 16 + lane15) * SEQ + jv);
    accv[0] = __builtin_amdgcn_mfma_f32_16x16x32_bf16(pa, v0, accv[0], 0, 0, 0);
    accv[1] = __builtin_amdgcn_mfma_f32_16x16x32_bf16(pa, v1, accv[1], 0, 0, 0);
  }

  #pragma unroll
  for (int r = 0; r < 4; ++r){
    float v = dsum[r];
    v += __shfl_xor(v, 1); v += __shfl_xor(v, 2);
    v += __shfl_xor(v, 4); v += __shfl_xor(v, 8);
    dsum[r] = v;
  }
  #pragma unroll
  for (int r = 0; r < 4; ++r){
    int i = s0 + laneh * 4 + r;
    float dn = (float)SEQ + dsum[r];
    float o0 = (accv[0][r] + vs0) / dn;
    float o1 = (accv[1][r] + vs1) / dn;
    size_t base = (size_t)(b * SEQ + i) * DIMX + h * HDIM;
    ao[base + lane15]      = f2bf(o0);
    ao[base + 16 + lane15] = f2bf(o1);
  }
}

// ---------- K5: LayerNorm over 512, one wave per row ----------
__global__ void k_ln(const float* __restrict__ y, const float* __restrict__ gamma,
                     const float* __restrict__ beta, float* __restrict__ out){
  int wid = threadIdx.x >> 6, lane = threadIdx.x & 63;
  int row = blockIdx.x * 4 + wid;
  const float4* yp = (const float4*)(y + (size_t)row * DIMX);
  float4 a = yp[lane], c = yp[lane + 64];
  float s  = a.x + a.y + a.z + a.w + c.x + c.y + c.z + c.w;
  float ss = a.x*a.x + a.y*a.y + a.z*a.z + a.w*a.w + c.x*c.x + c.y*c.y + c.z*c.z + c.w*c.w;
  #pragma unroll
  for (int m = 1; m < 64; m <<= 1){ s += __shfl_xor(s, m); ss += __shfl_xor(ss, m); }
  float mu = s * (1.f / DIMX);
  float var = ss * (1.f / DIMX) - mu * mu;
  float inv = rsqrtf(var + 1e-5f);
  const float4* gp = (const float4*)gamma;
  const float4* bp = (const float4*)beta;
  float4 g0 = gp[lane], g1 = gp[lane + 64];
  float4 b0 = bp[lane], b1 = bp[lane + 64];
  float4 o0, o1;
  o0.x = (a.x - mu) * inv * g0.x + b0.x; o0.y = (a.y - mu) * inv * g0.y + b0.y;
  o0.z = (a.z - mu) * inv * g0.z + b0.z; o0.w = (a.w - mu) * inv * g0.w + b0.w;
  o1.x = (c.x - mu) * inv * g1.x + b1.x; o1.y = (c.y - mu) * inv * g1.y + b1.y;
  o1.z = (c.z - mu) * inv * g1.z + b1.z; o1.w = (c.w - mu) * inv * g1.w + b1.w;
  float4* op = (float4*)(out + (size_t)row * DIMX);
  op[lane] = o0; op[lane + 64] = o1;
}

extern "C" void kernel_launch(void* const* d_in, const int* in_sizes, int n_in,
                              void* d_out, int out_size, void* d_ws, size_t ws_size,
                              hipStream_t stream){
  const float* x      = (const float*)d_in[0];
  const float* W_qkv  = (const float*)d_in[1];
  const float* b_qkv  = (const float*)d_in[2];
  const float* W_out  = (const float*)d_in[3];
  const float* b_out  = (const float*)d_in[4];
  const float* gamma  = (const float*)d_in[5];
  const float* beta   = (const float*)d_in[6];
  float* out = (float*)d_out;

  char* ws = (char*)d_ws;
  size_t off = 0;
  auto alloc = [&](size_t bytes){ void* p = ws + off; off += (bytes + 255) & ~(size_t)255; return p; };
  unsigned short* xb  = (unsigned short*)alloc((size_t)MTOT * DIMX * 2);
  unsigned short* wqt = (unsigned short*)alloc((size_t)1024 * 512 * 2);
  unsigned short* wot = (unsigned short*)alloc((size_t)512 * 512 * 2);
  unsigned short* qb  = (unsigned short*)alloc((size_t)MTOT * DIMX * 2);
  unsigned short* kb  = (unsigned short*)alloc((size_t)MTOT * DIMX * 2);
  unsigned short* vb  = (unsigned short*)alloc((size_t)MTOT * DIMX * 2);
  unsigned short* vt  = (unsigned short*)alloc((size_t)32 * HDIM * SEQ * 2);
  float*          vsm = (float*)alloc((size_t)8 * 32 * HDIM * 4);
  unsigned short* ao  = (unsigned short*)alloc((size_t)MTOT * DIMX * 2);
  float*          yb  = (float*)alloc((size_t)MTOT * DIMX * 4);

  k_cvt <<<MTOT * DIMX / 8 / 256, 256, 0, stream>>>(x, xb, MTOT * DIMX / 8);
  k_twt <<<dim3(48, 16), dim3(32, 8), 0, stream>>>(W_qkv, wqt, W_out, wot);
  k_gemm<0, 64, 8><<<dim3(64, 8), 256, 0, stream>>>(xb, wqt, b_qkv, qb, kb, vb, nullptr, nullptr);
  k_vt  <<<dim3(8, 32), 256, 0, stream>>>(vb, vt, vsm);
  k_attn<<<dim3(32, 32), 256, 0, stream>>>(qb, kb, vt, vsm, ao);
  k_gemm<1, 32, 4><<<dim3(128, 4), 256, 0, stream>>>(ao, wot, b_out, qb, kb, vb, x, yb);
  k_ln  <<<MTOT / 4, 256, 0, stream>>>(yb, gamma, beta, out);
}

// Round 5
// 56.062 us; speedup vs baseline: 3.2341x; 1.7235x over previous
//
#include <hip/hip_runtime.h>
#include <cstdint>
#include <cstddef>

#define DIMX 512
#define HDIM 32
#define NHEADS 16
#define SEQ 2048
#define BATCH 2
#define MTOT (BATCH*SEQ)   // 4096
#define WIN 64
#define QSCALE 0.17677669529663687f  // 32^-0.5

typedef __bf16 bf16x8 __attribute__((ext_vector_type(8)));
typedef float f32x4 __attribute__((ext_vector_type(4)));

__device__ __forceinline__ unsigned short f2bf(float f){
  unsigned u = __builtin_bit_cast(unsigned, f);
  u += 0x7FFFu + ((u >> 16) & 1u);          // RNE
  return (unsigned short)(u >> 16);
}
__device__ __forceinline__ float bf2f(unsigned short s){
  return __builtin_bit_cast(float, ((unsigned)s) << 16);
}
__device__ __forceinline__ unsigned pk(float a, float b){
  return (unsigned)f2bf(a) | ((unsigned)f2bf(b) << 16);
}

// async global->LDS, 16B per lane; dest is wave-uniform base + lane*16 (HW)
__device__ __forceinline__ void gl_lds16(const void* g, void* l){
  __builtin_amdgcn_global_load_lds(
      (const __attribute__((address_space(1))) unsigned*)g,
      (__attribute__((address_space(3))) unsigned*)(unsigned)(unsigned long long)l,
      16, 0, 0);
}

// ---------- K0a: fp32 -> bf16, 8 elems/thread ----------
__global__ void k_cvt(const float* __restrict__ src, unsigned short* __restrict__ dst, int n8){
  int i = blockIdx.x * blockDim.x + threadIdx.x;
  if (i >= n8) return;
  const float4* p = (const float4*)src + (size_t)i * 2;
  float4 a = p[0], b = p[1];
  uint4 o;
  o.x = pk(a.x, a.y); o.y = pk(a.z, a.w);
  o.z = pk(b.x, b.y); o.w = pk(b.z, b.w);
  ((uint4*)dst)[i] = o;
}

// ---------- K0b: both weight transposes in one launch ----------
__global__ void k_twt(const float* __restrict__ Wq, unsigned short* __restrict__ Wqt,
                      const float* __restrict__ Wo, unsigned short* __restrict__ Wot){
  __shared__ float tile[32][33];
  int bx = blockIdx.x;
  const float* W; unsigned short* Wt; int N, n0;
  if (bx < 32){ W = Wq; Wt = Wqt; N = 1024; n0 = bx * 32; }
  else        { W = Wo; Wt = Wot; N = 512;  n0 = (bx - 32) * 32; }
  int k0 = blockIdx.y * 32;
  int tx = threadIdx.x, ty = threadIdx.y;   // block 32x8
  #pragma unroll
  for (int r = 0; r < 32; r += 8)
    tile[ty + r][tx] = W[(size_t)(k0 + ty + r) * N + n0 + tx];
  __syncthreads();
  #pragma unroll
  for (int r = 0; r < 32; r += 8)
    Wt[(size_t)(n0 + ty + r) * 512 + k0 + tx] = f2bf(tile[tx][ty + r]);
}

// ---------- K1/K4: bf16 MFMA GEMM, m97-style 2-phase dbuf global_load_lds ----------
// 64x64 tile, BK=64, 4 waves (2x2 of 32x32). LDS linear dest + inverse-swizzled
// global source + swizzled ds_read (rule #21): conflict-free, zero cost.
// MODE 0: qkv epilogue (silu*scale -> qb, tanh -> kb, identity -> vb), NBN=16
// MODE 1: out-proj epilogue: y = acc + bias + xres (fp32), NBN=8
template<int MODE, int NBN>
__launch_bounds__(256)
__global__ void k_gemm(const unsigned short* __restrict__ A,
                       const unsigned short* __restrict__ Bt,
                       const float* __restrict__ bias,
                       unsigned short* __restrict__ qb,
                       unsigned short* __restrict__ kb,
                       unsigned short* __restrict__ vb,
                       const float* __restrict__ xres,
                       float* __restrict__ y)
{
  const int K = 512;
  constexpr int NWG = 64 * NBN;
  // [buf][A/B][64 rows][64 cols] bf16; row = 128B = 8 chunks of 16B
  __shared__ __align__(16) unsigned short lds[2][2][64 * 64];
  int tid = threadIdx.x;
  int wid = tid >> 6, lane = tid & 63;
  int wm = wid >> 1, wn = wid & 1;
  int lane15 = lane & 15, laneh = lane >> 4;

  // XCD-aware bijective swizzle (NWG % 8 == 0)
  int g = blockIdx.x;
  int gwi = (g & 7) * (NWG / 8) + (g >> 3);
  int bm = gwi / NBN, bn = gwi % NBN;

  f32x4 acc[2][2] = {};

  // staging geometry: 8 chunks of 8 rows each per matrix; wave wid does chunks
  // {wid*2, wid*2+1}. lane covers row cidx*8 + (lane>>3), LDS pos lane&7.
  int srow_off = lane >> 3;           // 0..7
  int spos     = lane & 7;            // 0..7

  auto STAGE = [&](int buf, int kt){
    int k0 = kt * 64;
    #pragma unroll
    for (int c = 0; c < 2; ++c){
      int cidx = wid * 2 + c;
      int r = cidx * 8 + srow_off;
      int ch = spos ^ (r & 7);        // inverse-swizzled source chunk
      gl_lds16(A  + (size_t)(bm * 64 + r) * K + k0 + ch * 8, &lds[buf][0][cidx * 512]);
      gl_lds16(Bt + (size_t)(bn * 64 + r) * K + k0 + ch * 8, &lds[buf][1][cidx * 512]);
    }
  };

  auto COMPUTE = [&](int buf){
    #pragma unroll
    for (int kh = 0; kh < 2; ++kh){
      int chunk = kh * 4 + laneh;
      bf16x8 af[2], bf[2];
      #pragma unroll
      for (int mi = 0; mi < 2; ++mi){
        int row = wm * 32 + mi * 16 + lane15;
        af[mi] = *(const bf16x8*)&lds[buf][0][row * 64 + (chunk ^ (row & 7)) * 8];
      }
      #pragma unroll
      for (int ni = 0; ni < 2; ++ni){
        int row = wn * 32 + ni * 16 + lane15;
        bf[ni] = *(const bf16x8*)&lds[buf][1][row * 64 + (chunk ^ (row & 7)) * 8];
      }
      #pragma unroll
      for (int mi = 0; mi < 2; ++mi)
        #pragma unroll
        for (int ni = 0; ni < 2; ++ni)
          acc[mi][ni] = __builtin_amdgcn_mfma_f32_16x16x32_bf16(af[mi], bf[ni], acc[mi][ni], 0, 0, 0);
    }
  };

  STAGE(0, 0);
  __syncthreads();                    // implicit vmcnt(0) drain: buf0 ready
  #pragma unroll
  for (int kt = 0; kt < 8; ++kt){
    if (kt < 7) STAGE((kt + 1) & 1, kt + 1);   // async, flies under compute
    COMPUTE(kt & 1);
    __syncthreads();                  // drains stage loads + guards buffer reuse
  }

  #pragma unroll
  for (int mi = 0; mi < 2; ++mi){
    #pragma unroll
    for (int ni = 0; ni < 2; ++ni){
      #pragma unroll
      for (int r = 0; r < 4; ++r){
        int m = bm * 64 + wm * 32 + mi * 16 + laneh * 4 + r;
        int n = bn * 64 + wn * 32 + ni * 16 + lane15;
        float val = acc[mi][ni][r] + bias[n];
        if (MODE == 0){
          if (n < DIMX){
            float s = val / (1.0f + __expf(-val)) * QSCALE;  // silu * scale
            float t = tanhf(val);
            qb[(size_t)m * DIMX + n] = f2bf(s);
            kb[(size_t)m * DIMX + n] = f2bf(t);
          } else {
            vb[(size_t)m * DIMX + (n - DIMX)] = f2bf(val);
          }
        } else {
          size_t idx = (size_t)m * DIMX + n;
          y[idx] = val + xres[idx];
        }
      }
    }
  }
}

// ---------- K2: v [m][512] -> vt [bh*32+d][2048] (bf16) + partial colsums ----------
__global__ void k_vt(const unsigned short* __restrict__ vb, unsigned short* __restrict__ vt,
                     float* __restrict__ vsum_p){
  __shared__ unsigned short tile[256][34];  // pad to kill bank conflicts
  int sc = blockIdx.x;        // 0..7  (256-row s chunk)
  int bh = blockIdx.y;        // 0..31
  int b = bh >> 4, h = bh & 15;
  int tid = threadIdx.x;
  int d = tid & 31, si = tid >> 5;
  #pragma unroll
  for (int i = 0; i < 32; ++i){
    int sl = i * 8 + si;
    tile[sl][d] = vb[(size_t)(b * SEQ + sc * 256 + sl) * DIMX + h * HDIM + d];
  }
  __syncthreads();
  int wv = tid >> 6, lane = tid & 63;   // wave wv handles dd = ii*4+wv
  #pragma unroll
  for (int ii = 0; ii < 8; ++ii){
    int dd = ii * 4 + wv;
    float acc = 0.f;
    #pragma unroll
    for (int c = 0; c < 4; ++c){
      unsigned short u = tile[c * 64 + lane][dd];
      vt[(size_t)(bh * HDIM + dd) * SEQ + sc * 256 + c * 64 + lane] = u;
      acc += bf2f(u);
    }
    #pragma unroll
    for (int m = 1; m < 64; m <<= 1) acc += __shfl_xor(acc, m);
    if (lane == 0) vsum_p[(sc * 32 + bh) * HDIM + dd] = acc;
  }
}

// ---------- K3: banded attention (e^s - 1 trick), MFMA, 9 k-tiles ----------
__launch_bounds__(256)
__global__ void k_attn(const unsigned short* __restrict__ qb,
                       const unsigned short* __restrict__ kb,
                       const unsigned short* __restrict__ vt,
                       const float* __restrict__ vsum_p,
                       unsigned short* __restrict__ ao)
{
  __shared__ unsigned short p_lds[4][16][40];   // per-wave P staging, padded
  int tid = threadIdx.x, wid = tid >> 6, lane = tid & 63;
  int lane15 = lane & 15, laneh = lane >> 4;
  int bh = blockIdx.y, b = bh >> 4, h = bh & 15;
  int s0 = blockIdx.x * 64 + wid * 16;

  bf16x8 qf = *(const bf16x8*)(qb + (size_t)(b * SEQ + s0 + lane15) * DIMX + h * HDIM + laneh * 8);
  float vs0 = 0.f, vs1 = 0.f;
  #pragma unroll
  for (int c = 0; c < 8; ++c){
    vs0 += vsum_p[(c * 32 + bh) * HDIM + lane15];
    vs1 += vsum_p[(c * 32 + bh) * HDIM + 16 + lane15];
  }

  f32x4 accv[2] = {};
  float dsum[4] = {0.f, 0.f, 0.f, 0.f};

  // band |i-j|<=64 with i in [s0, s0+16) touches j in [s0-64, s0+80) = 9 tiles
  for (int jt = 0; jt < 9; ++jt){
    int j0 = s0 - 64 + jt * 16;
    int jc = min(max(j0 + lane15, 0), SEQ - 1);
    bf16x8 kf = *(const bf16x8*)(kb + (size_t)(b * SEQ + jc) * DIMX + h * HDIM + laneh * 8);
    f32x4 z = {0.f, 0.f, 0.f, 0.f};
    f32x4 sv = __builtin_amdgcn_mfma_f32_16x16x32_bf16(qf, kf, z, 0, 0, 0);
    #pragma unroll
    for (int r = 0; r < 4; ++r){
      int i = s0 + laneh * 4 + r;
      int j = j0 + lane15;
      int dj = i - j;
      bool inb = (dj <= WIN) && (dj >= -WIN) && (j >= 0) && (j < SEQ);
      float w = inb ? (__expf(sv[r]) - 1.0f) : 0.0f;
      dsum[r] += w;
      p_lds[wid][laneh * 4 + r][(jt & 1) * 16 + lane15] = f2bf(w);
    }
    if (jt & 1){
      int jc0 = j0 - 16;   // 32-wide chunk base
      bf16x8 pa = *(const bf16x8*)&p_lds[wid][lane15][laneh * 8];
      int jv = min(max(jc0 + laneh * 8, 0), SEQ - 8);
      bf16x8 v0 = *(const bf16x8*)(vt + (size_t)(bh * HDIM + lane15) * SEQ + jv);
      bf16x8 v1 = *(const bf16x8*)(vt + (size_t)(bh * HDIM + 16 + lane15) * SEQ + jv);
      accv[0] = __builtin_amdgcn_mfma_f32_16x16x32_bf16(pa, v0, accv[0], 0, 0, 0);
      accv[1] = __builtin_amdgcn_mfma_f32_16x16x32_bf16(pa, v1, accv[1], 0, 0, 0);
    }
  }
  // tail PV for tile 8 (cols 0..15); zero cols 16..31 first
  {
    #pragma unroll
    for (int r = 0; r < 4; ++r)
      p_lds[wid][laneh * 4 + r][16 + lane15] = 0;
    int jc0 = s0 + 64;
    bf16x8 pa = *(const bf16x8*)&p_lds[wid][lane15][laneh * 8];
    int jv = min(max(jc0 + laneh * 8, 0), SEQ - 8);
    bf16x8 v0 = *(const bf16x8*)(vt + (size_t)(bh * HDIM + lane15) * SEQ + jv);
    bf16x8 v1 = *(const bf16x8*)(vt + (size_t)(bh * HDIM + 16 + lane15) * SEQ + jv);
    accv[0] = __builtin_amdgcn_mfma_f32_16x16x32_bf16(pa, v0, accv[0], 0, 0, 0);
    accv[1] = __builtin_amdgcn_mfma_f32_16x16x32_bf16(pa, v1, accv[1], 0, 0, 0);
  }

  #pragma unroll
  for (int r = 0; r < 4; ++r){
    float v = dsum[r];
    v += __shfl_xor(v, 1); v += __shfl_xor(v, 2);
    v += __shfl_xor(v, 4); v += __shfl_xor(v, 8);
    dsum[r] = v;
  }
  #pragma unroll
  for (int r = 0; r < 4; ++r){
    int i = s0 + laneh * 4 + r;
    float dn = (float)SEQ + dsum[r];
    float o0 = (accv[0][r] + vs0) / dn;
    float o1 = (accv[1][r] + vs1) / dn;
    size_t base = (size_t)(b * SEQ + i) * DIMX + h * HDIM;
    ao[base + lane15]      = f2bf(o0);
    ao[base + 16 + lane15] = f2bf(o1);
  }
}

// ---------- K5: LayerNorm over 512, one wave per row ----------
__global__ void k_ln(const float* __restrict__ y, const float* __restrict__ gamma,
                     const float* __restrict__ beta, float* __restrict__ out){
  int wid = threadIdx.x >> 6, lane = threadIdx.x & 63;
  int row = blockIdx.x * 4 + wid;
  const float4* yp = (const float4*)(y + (size_t)row * DIMX);
  float4 a = yp[lane], c = yp[lane + 64];
  float s  = a.x + a.y + a.z + a.w + c.x + c.y + c.z + c.w;
  float ss = a.x*a.x + a.y*a.y + a.z*a.z + a.w*a.w + c.x*c.x + c.y*c.y + c.z*c.z + c.w*c.w;
  #pragma unroll
  for (int m = 1; m < 64; m <<= 1){ s += __shfl_xor(s, m); ss += __shfl_xor(ss, m); }
  float mu = s * (1.f / DIMX);
  float var = ss * (1.f / DIMX) - mu * mu;
  float inv = rsqrtf(var + 1e-5f);
  const float4* gp = (const float4*)gamma;
  const float4* bp = (const float4*)beta;
  float4 g0 = gp[lane], g1 = gp[lane + 64];
  float4 b0 = bp[lane], b1 = bp[lane + 64];
  float4 o0, o1;
  o0.x = (a.x - mu) * inv * g0.x + b0.x; o0.y = (a.y - mu) * inv * g0.y + b0.y;
  o0.z = (a.z - mu) * inv * g0.z + b0.z; o0.w = (a.w - mu) * inv * g0.w + b0.w;
  o1.x = (c.x - mu) * inv * g1.x + b1.x; o1.y = (c.y - mu) * inv * g1.y + b1.y;
  o1.z = (c.z - mu) * inv * g1.z + b1.z; o1.w = (c.w - mu) * inv * g1.w + b1.w;
  float4* op = (float4*)(out + (size_t)row * DIMX);
  op[lane] = o0; op[lane + 64] = o1;
}

extern "C" void kernel_launch(void* const* d_in, const int* in_sizes, int n_in,
                              void* d_out, int out_size, void* d_ws, size_t ws_size,
                              hipStream_t stream){
  const float* x      = (const float*)d_in[0];
  const float* W_qkv  = (const float*)d_in[1];
  const float* b_qkv  = (const float*)d_in[2];
  const float* W_out  = (const float*)d_in[3];
  const float* b_out  = (const float*)d_in[4];
  const float* gamma  = (const float*)d_in[5];
  const float* beta   = (const float*)d_in[6];
  float* out = (float*)d_out;

  char* ws = (char*)d_ws;
  size_t off = 0;
  auto alloc = [&](size_t bytes){ void* p = ws + off; off += (bytes + 255) & ~(size_t)255; return p; };
  unsigned short* xb  = (unsigned short*)alloc((size_t)MTOT * DIMX * 2);
  unsigned short* wqt = (unsigned short*)alloc((size_t)1024 * 512 * 2);
  unsigned short* wot = (unsigned short*)alloc((size_t)512 * 512 * 2);
  unsigned short* qb  = (unsigned short*)alloc((size_t)MTOT * DIMX * 2);
  unsigned short* kb  = (unsigned short*)alloc((size_t)MTOT * DIMX * 2);
  unsigned short* vb  = (unsigned short*)alloc((size_t)MTOT * DIMX * 2);
  unsigned short* vt  = (unsigned short*)alloc((size_t)32 * HDIM * SEQ * 2);
  float*          vsm = (float*)alloc((size_t)8 * 32 * HDIM * 4);
  unsigned short* ao  = (unsigned short*)alloc((size_t)MTOT * DIMX * 2);
  float*          yb  = (float*)alloc((size_t)MTOT * DIMX * 4);

  k_cvt <<<MTOT * DIMX / 8 / 256, 256, 0, stream>>>(x, xb, MTOT * DIMX / 8);
  k_twt <<<dim3(48, 16), dim3(32, 8), 0, stream>>>(W_qkv, wqt, W_out, wot);
  k_gemm<0, 16><<<1024, 256, 0, stream>>>(xb, wqt, b_qkv, qb, kb, vb, nullptr, nullptr);
  k_vt  <<<dim3(8, 32), 256, 0, stream>>>(vb, vt, vsm);
  k_attn<<<dim3(32, 32), 256, 0, stream>>>(qb, kb, vt, vsm, ao);
  k_gemm<1, 8><<<512, 256, 0, stream>>>(ao, wot, b_out, qb, kb, vb, x, yb);
  k_ln  <<<MTOT / 4, 256, 0, stream>>>(yb, gamma, beta, out);
}

// Round 6
// 51.589 us; speedup vs baseline: 3.5146x; 1.0867x over previous
//
#include <hip/hip_runtime.h>
#include <cstdint>
#include <cstddef>

#define DIMX 512
#define HDIM 32
#define NHEADS 16
#define SEQ 2048
#define BATCH 2
#define MTOT (BATCH*SEQ)   // 4096
#define WIN 64
#define QSCALE 0.17677669529663687f  // 32^-0.5

typedef __bf16 bf16x8 __attribute__((ext_vector_type(8)));
typedef float f32x4 __attribute__((ext_vector_type(4)));

__device__ __forceinline__ unsigned short f2bf(float f){
  unsigned u = __builtin_bit_cast(unsigned, f);
  u += 0x7FFFu + ((u >> 16) & 1u);          // RNE
  return (unsigned short)(u >> 16);
}
__device__ __forceinline__ float bf2f(unsigned short s){
  return __builtin_bit_cast(float, ((unsigned)s) << 16);
}
__device__ __forceinline__ unsigned pk(float a, float b){
  return (unsigned)f2bf(a) | ((unsigned)f2bf(b) << 16);
}

// async global->LDS, 16B per lane; dest is wave-uniform base + lane*16 (HW)
__device__ __forceinline__ void gl_lds16(const void* g, void* l){
  __builtin_amdgcn_global_load_lds(
      (const __attribute__((address_space(1))) unsigned*)g,
      (__attribute__((address_space(3))) unsigned*)(unsigned)(unsigned long long)l,
      16, 0, 0);
}

// ---------- K0: fused x->bf16 convert (blocks 0..1023) + weight transposes ----------
__global__ void k_prep(const float* __restrict__ x, unsigned short* __restrict__ xb,
                       const float* __restrict__ Wq, unsigned short* __restrict__ Wqt,
                       const float* __restrict__ Wo, unsigned short* __restrict__ Wot){
  int bx = blockIdx.x;
  if (bx < 1024){                      // cvt: 8 elems/thread, 1024*256*8 = 2M elems
    int i = bx * 256 + threadIdx.x;
    const float4* p = (const float4*)x + (size_t)i * 2;
    float4 a = p[0], b = p[1];
    uint4 o;
    o.x = pk(a.x, a.y); o.y = pk(a.z, a.w);
    o.z = pk(b.x, b.y); o.w = pk(b.z, b.w);
    ((uint4*)xb)[i] = o;
    return;
  }
  __shared__ float tile[32][33];
  int i = bx - 1024;                   // 0..767 -> (bxx 0..47, byy 0..15)
  int bxx = i % 48, byy = i / 48;
  const float* W; unsigned short* Wt; int N, n0;
  if (bxx < 32){ W = Wq; Wt = Wqt; N = 1024; n0 = bxx * 32; }
  else         { W = Wo; Wt = Wot; N = 512;  n0 = (bxx - 32) * 32; }
  int k0 = byy * 32;
  int tx = threadIdx.x & 31, ty = threadIdx.x >> 5;   // 32x8
  #pragma unroll
  for (int r = 0; r < 32; r += 8)
    tile[ty + r][tx] = W[(size_t)(k0 + ty + r) * N + n0 + tx];
  __syncthreads();
  #pragma unroll
  for (int r = 0; r < 32; r += 8)
    Wt[(size_t)(n0 + ty + r) * 512 + k0 + tx] = f2bf(tile[tx][ty + r]);
}

// ---------- K1/K4: bf16 MFMA GEMM, m97-style 2-phase dbuf global_load_lds ----------
// 64x64 tile, BK=64, 4 waves (2x2 of 32x32). Linear LDS dest + inverse-swizzled
// global source + swizzled ds_read (rule #21).
// MODE 0, bn<8 : silu*scale -> qb, tanh -> kb
// MODE 0, bn>=8: V-tile -> LDS transpose -> vt [bh*32+d][s] + vsum_p partials
// MODE 1       : y = acc + bias + xres (fp32)
template<int MODE, int NBN>
__launch_bounds__(256)
__global__ void k_gemm(const unsigned short* __restrict__ A,
                       const unsigned short* __restrict__ Bt,
                       const float* __restrict__ bias,
                       unsigned short* __restrict__ qb,
                       unsigned short* __restrict__ kb,
                       unsigned short* __restrict__ vt,
                       float* __restrict__ vsum_p,
                       const float* __restrict__ xres,
                       float* __restrict__ y)
{
  const int K = 512;
  constexpr int NWG = 64 * NBN;
  __shared__ __align__(16) unsigned short lds[2][2][64 * 64];   // 32 KB
  int tid = threadIdx.x;
  int wid = tid >> 6, lane = tid & 63;
  int wm = wid >> 1, wn = wid & 1;
  int lane15 = lane & 15, laneh = lane >> 4;

  // XCD-aware bijective swizzle (NWG % 8 == 0)
  int g = blockIdx.x;
  int gwi = (g & 7) * (NWG / 8) + (g >> 3);
  int bm = gwi / NBN, bn = gwi % NBN;

  f32x4 acc[2][2] = {};

  int srow_off = lane >> 3;           // 0..7
  int spos     = lane & 7;            // 0..7

  auto STAGE = [&](int buf, int kt){
    int k0 = kt * 64;
    #pragma unroll
    for (int c = 0; c < 2; ++c){
      int cidx = wid * 2 + c;
      int r = cidx * 8 + srow_off;
      int ch = spos ^ (r & 7);        // inverse-swizzled source chunk
      gl_lds16(A  + (size_t)(bm * 64 + r) * K + k0 + ch * 8, &lds[buf][0][cidx * 512]);
      gl_lds16(Bt + (size_t)(bn * 64 + r) * K + k0 + ch * 8, &lds[buf][1][cidx * 512]);
    }
  };

  auto COMPUTE = [&](int buf){
    #pragma unroll
    for (int kh = 0; kh < 2; ++kh){
      int chunk = kh * 4 + laneh;
      bf16x8 af[2], bf[2];
      #pragma unroll
      for (int mi = 0; mi < 2; ++mi){
        int row = wm * 32 + mi * 16 + lane15;
        af[mi] = *(const bf16x8*)&lds[buf][0][row * 64 + (chunk ^ (row & 7)) * 8];
      }
      #pragma unroll
      for (int ni = 0; ni < 2; ++ni){
        int row = wn * 32 + ni * 16 + lane15;
        bf[ni] = *(const bf16x8*)&lds[buf][1][row * 64 + (chunk ^ (row & 7)) * 8];
      }
      #pragma unroll
      for (int mi = 0; mi < 2; ++mi)
        #pragma unroll
        for (int ni = 0; ni < 2; ++ni)
          acc[mi][ni] = __builtin_amdgcn_mfma_f32_16x16x32_bf16(af[mi], bf[ni], acc[mi][ni], 0, 0, 0);
    }
  };

  STAGE(0, 0);
  __syncthreads();
  #pragma unroll
  for (int kt = 0; kt < 8; ++kt){
    if (kt < 7) STAGE((kt + 1) & 1, kt + 1);
    COMPUTE(kt & 1);
    __syncthreads();
  }

  if (MODE == 0 && bn >= 8){
    // ---- V path: transpose 64x64 tile in LDS, write vt + vsum partials ----
    unsigned short (*tp)[72] = (unsigned short (*)[72])&lds[0][0][0];  // 9.2 KB
    #pragma unroll
    for (int mi = 0; mi < 2; ++mi)
      #pragma unroll
      for (int ni = 0; ni < 2; ++ni)
        #pragma unroll
        for (int r = 0; r < 4; ++r){
          int ml = wm * 32 + mi * 16 + laneh * 4 + r;
          int nl = wn * 32 + ni * 16 + lane15;
          tp[nl][ml] = f2bf(acc[mi][ni][r] + bias[bn * 64 + nl]);
        }
    __syncthreads();
    int nl = tid >> 2, q = tid & 3;
    int h = (bn - 8) * 2 + (nl >> 5), d = nl & 31;
    int bh = (bm >> 5) * 16 + h;        // b = bm/32
    int sc = bm & 31;                   // 64-row s-chunk within batch
    unsigned short vals[16];
    float ssum = 0.f;
    #pragma unroll
    for (int j = 0; j < 16; ++j){ vals[j] = tp[nl][q * 16 + j]; ssum += bf2f(vals[j]); }
    ssum += __shfl_xor(ssum, 1); ssum += __shfl_xor(ssum, 2);
    uint4 o0, o1;
    o0.x = (unsigned)vals[0]  | ((unsigned)vals[1]  << 16);
    o0.y = (unsigned)vals[2]  | ((unsigned)vals[3]  << 16);
    o0.z = (unsigned)vals[4]  | ((unsigned)vals[5]  << 16);
    o0.w = (unsigned)vals[6]  | ((unsigned)vals[7]  << 16);
    o1.x = (unsigned)vals[8]  | ((unsigned)vals[9]  << 16);
    o1.y = (unsigned)vals[10] | ((unsigned)vals[11] << 16);
    o1.z = (unsigned)vals[12] | ((unsigned)vals[13] << 16);
    o1.w = (unsigned)vals[14] | ((unsigned)vals[15] << 16);
    size_t vtoff = (size_t)(bh * HDIM + d) * SEQ + sc * 64 + q * 16;
    *(uint4*)(vt + vtoff) = o0;
    *(uint4*)(vt + vtoff + 8) = o1;
    if (q == 0) vsum_p[(sc * 32 + bh) * HDIM + d] = ssum;
  } else {
    #pragma unroll
    for (int mi = 0; mi < 2; ++mi){
      #pragma unroll
      for (int ni = 0; ni < 2; ++ni){
        #pragma unroll
        for (int r = 0; r < 4; ++r){
          int m = bm * 64 + wm * 32 + mi * 16 + laneh * 4 + r;
          int n = bn * 64 + wn * 32 + ni * 16 + lane15;
          float val = acc[mi][ni][r] + bias[n];
          if (MODE == 0){
            float s = val / (1.0f + __expf(-val)) * QSCALE;  // silu * scale
            float t = tanhf(val);
            qb[(size_t)m * DIMX + n] = f2bf(s);
            kb[(size_t)m * DIMX + n] = f2bf(t);
          } else {
            size_t idx = (size_t)m * DIMX + n;
            y[idx] = val + xres[idx];
          }
        }
      }
    }
  }
}

// ---------- K3: banded attention (e^s - 1 trick), MFMA, 9 k-tiles ----------
__launch_bounds__(256)
__global__ void k_attn(const unsigned short* __restrict__ qb,
                       const unsigned short* __restrict__ kb,
                       const unsigned short* __restrict__ vt,
                       const float* __restrict__ vsum_p,
                       unsigned short* __restrict__ ao)
{
  __shared__ unsigned short p_lds[4][16][40];   // per-wave P staging, padded
  int tid = threadIdx.x, wid = tid >> 6, lane = tid & 63;
  int lane15 = lane & 15, laneh = lane >> 4;
  int bh = blockIdx.y, b = bh >> 4, h = bh & 15;
  int s0 = blockIdx.x * 64 + wid * 16;

  bf16x8 qf = *(const bf16x8*)(qb + (size_t)(b * SEQ + s0 + lane15) * DIMX + h * HDIM + laneh * 8);
  float vs0 = 0.f, vs1 = 0.f;
  #pragma unroll
  for (int c = 0; c < 32; ++c){
    vs0 += vsum_p[(c * 32 + bh) * HDIM + lane15];
    vs1 += vsum_p[(c * 32 + bh) * HDIM + 16 + lane15];
  }

  f32x4 accv[2] = {};
  float dsum[4] = {0.f, 0.f, 0.f, 0.f};

  // band |i-j|<=64 with i in [s0, s0+16) touches j in [s0-64, s0+80) = 9 tiles
  for (int jt = 0; jt < 9; ++jt){
    int j0 = s0 - 64 + jt * 16;
    int jc = min(max(j0 + lane15, 0), SEQ - 1);
    bf16x8 kf = *(const bf16x8*)(kb + (size_t)(b * SEQ + jc) * DIMX + h * HDIM + laneh * 8);
    f32x4 z = {0.f, 0.f, 0.f, 0.f};
    f32x4 sv = __builtin_amdgcn_mfma_f32_16x16x32_bf16(qf, kf, z, 0, 0, 0);
    #pragma unroll
    for (int r = 0; r < 4; ++r){
      int i = s0 + laneh * 4 + r;
      int j = j0 + lane15;
      int dj = i - j;
      bool inb = (dj <= WIN) && (dj >= -WIN) && (j >= 0) && (j < SEQ);
      float w = inb ? (__expf(sv[r]) - 1.0f) : 0.0f;
      dsum[r] += w;
      p_lds[wid][laneh * 4 + r][(jt & 1) * 16 + lane15] = f2bf(w);
    }
    if (jt & 1){
      int jc0 = j0 - 16;   // 32-wide chunk base
      bf16x8 pa = *(const bf16x8*)&p_lds[wid][lane15][laneh * 8];
      int jv = min(max(jc0 + laneh * 8, 0), SEQ - 8);
      bf16x8 v0 = *(const bf16x8*)(vt + (size_t)(bh * HDIM + lane15) * SEQ + jv);
      bf16x8 v1 = *(const bf16x8*)(vt + (size_t)(bh * HDIM + 16 + lane15) * SEQ + jv);
      accv[0] = __builtin_amdgcn_mfma_f32_16x16x32_bf16(pa, v0, accv[0], 0, 0, 0);
      accv[1] = __builtin_amdgcn_mfma_f32_16x16x32_bf16(pa, v1, accv[1], 0, 0, 0);
    }
  }
  // tail PV for tile 8 (cols 0..15); zero cols 16..31 first
  {
    #pragma unroll
    for (int r = 0; r < 4; ++r)
      p_lds[wid][laneh * 4 + r][16 + lane15] = 0;
    int jc0 = s0 + 64;
    bf16x8 pa = *(const bf16x8*)&p_lds[wid][lane15][laneh * 8];
    int jv = min(max(jc0 + laneh * 8, 0), SEQ - 8);
    bf16x8 v0 = *(const bf16x8*)(vt + (size_t)(bh * HDIM + lane15) * SEQ + jv);
    bf16x8 v1 = *(const bf16x8*)(vt + (size_t)(bh * HDIM + 16 + lane15) * SEQ + jv);
    accv[0] = __builtin_amdgcn_mfma_f32_16x16x32_bf16(pa, v0, accv[0], 0, 0, 0);
    accv[1] = __builtin_amdgcn_mfma_f32_16x16x32_bf16(pa, v1, accv[1], 0, 0, 0);
  }

  #pragma unroll
  for (int r = 0; r < 4; ++r){
    float v = dsum[r];
    v += __shfl_xor(v, 1); v += __shfl_xor(v, 2);
    v += __shfl_xor(v, 4); v += __shfl_xor(v, 8);
    dsum[r] = v;
  }
  #pragma unroll
  for (int r = 0; r < 4; ++r){
    int i = s0 + laneh * 4 + r;
    float dn = (float)SEQ + dsum[r];
    float o0 = (accv[0][r] + vs0) / dn;
    float o1 = (accv[1][r] + vs1) / dn;
    size_t base = (size_t)(b * SEQ + i) * DIMX + h * HDIM;
    ao[base + lane15]      = f2bf(o0);
    ao[base + 16 + lane15] = f2bf(o1);
  }
}

// ---------- K5: LayerNorm over 512, one wave per row ----------
__global__ void k_ln(const float* __restrict__ y, const float* __restrict__ gamma,
                     const float* __restrict__ beta, float* __restrict__ out){
  int wid = threadIdx.x >> 6, lane = threadIdx.x & 63;
  int row = blockIdx.x * 4 + wid;
  const float4* yp = (const float4*)(y + (size_t)row * DIMX);
  float4 a = yp[lane], c = yp[lane + 64];
  float s  = a.x + a.y + a.z + a.w + c.x + c.y + c.z + c.w;
  float ss = a.x*a.x + a.y*a.y + a.z*a.z + a.w*a.w + c.x*c.x + c.y*c.y + c.z*c.z + c.w*c.w;
  #pragma unroll
  for (int m = 1; m < 64; m <<= 1){ s += __shfl_xor(s, m); ss += __shfl_xor(ss, m); }
  float mu = s * (1.f / DIMX);
  float var = ss * (1.f / DIMX) - mu * mu;
  float inv = rsqrtf(var + 1e-5f);
  const float4* gp = (const float4*)gamma;
  const float4* bp = (const float4*)beta;
  float4 g0 = gp[lane], g1 = gp[lane + 64];
  float4 b0 = bp[lane], b1 = bp[lane + 64];
  float4 o0, o1;
  o0.x = (a.x - mu) * inv * g0.x + b0.x; o0.y = (a.y - mu) * inv * g0.y + b0.y;
  o0.z = (a.z - mu) * inv * g0.z + b0.z; o0.w = (a.w - mu) * inv * g0.w + b0.w;
  o1.x = (c.x - mu) * inv * g1.x + b1.x; o1.y = (c.y - mu) * inv * g1.y + b1.y;
  o1.z = (c.z - mu) * inv * g1.z + b1.z; o1.w = (c.w - mu) * inv * g1.w + b1.w;
  float4* op = (float4*)(out + (size_t)row * DIMX);
  op[lane] = o0; op[lane + 64] = o1;
}

extern "C" void kernel_launch(void* const* d_in, const int* in_sizes, int n_in,
                              void* d_out, int out_size, void* d_ws, size_t ws_size,
                              hipStream_t stream){
  const float* x      = (const float*)d_in[0];
  const float* W_qkv  = (const float*)d_in[1];
  const float* b_qkv  = (const float*)d_in[2];
  const float* W_out  = (const float*)d_in[3];
  const float* b_out  = (const float*)d_in[4];
  const float* gamma  = (const float*)d_in[5];
  const float* beta   = (const float*)d_in[6];
  float* out = (float*)d_out;

  char* ws = (char*)d_ws;
  size_t off = 0;
  auto alloc = [&](size_t bytes){ void* p = ws + off; off += (bytes + 255) & ~(size_t)255; return p; };
  unsigned short* xb  = (unsigned short*)alloc((size_t)MTOT * DIMX * 2);
  unsigned short* wqt = (unsigned short*)alloc((size_t)1024 * 512 * 2);
  unsigned short* wot = (unsigned short*)alloc((size_t)512 * 512 * 2);
  unsigned short* qb  = (unsigned short*)alloc((size_t)MTOT * DIMX * 2);
  unsigned short* kb  = (unsigned short*)alloc((size_t)MTOT * DIMX * 2);
  unsigned short* vt  = (unsigned short*)alloc((size_t)32 * HDIM * SEQ * 2);
  float*          vsm = (float*)alloc((size_t)32 * 32 * HDIM * 4);
  unsigned short* ao  = (unsigned short*)alloc((size_t)MTOT * DIMX * 2);
  float*          yb  = (float*)alloc((size_t)MTOT * DIMX * 4);

  k_prep<<<1792, 256, 0, stream>>>(x, xb, W_qkv, wqt, W_out, wot);
  k_gemm<0, 16><<<1024, 256, 0, stream>>>(xb, wqt, b_qkv, qb, kb, vt, vsm, nullptr, nullptr);
  k_attn<<<dim3(32, 32), 256, 0, stream>>>(qb, kb, vt, vsm, ao);
  k_gemm<1, 8><<<512, 256, 0, stream>>>(ao, wot, b_out, nullptr, nullptr, nullptr, nullptr, x, yb);
  k_ln  <<<MTOT / 4, 256, 0, stream>>>(yb, gamma, beta, out);
}

// Round 7
// 48.879 us; speedup vs baseline: 3.7094x; 1.0554x over previous
//
#include <hip/hip_runtime.h>
#include <cstdint>
#include <cstddef>

#define DIMX 512
#define HDIM 32
#define NHEADS 16
#define SEQ 2048
#define BATCH 2
#define MTOT (BATCH*SEQ)   // 4096
#define WIN 64
#define QSCALE 0.17677669529663687f  // 32^-0.5

typedef __bf16 bf16x8 __attribute__((ext_vector_type(8)));
typedef float f32x4 __attribute__((ext_vector_type(4)));

__device__ __forceinline__ unsigned short f2bf(float f){
  unsigned u = __builtin_bit_cast(unsigned, f);
  u += 0x7FFFu + ((u >> 16) & 1u);          // RNE
  return (unsigned short)(u >> 16);
}
__device__ __forceinline__ float bf2f(unsigned short s){
  return __builtin_bit_cast(float, ((unsigned)s) << 16);
}
__device__ __forceinline__ unsigned pk(float a, float b){
  return (unsigned)f2bf(a) | ((unsigned)f2bf(b) << 16);
}

// async global->LDS, 16B per lane; dest is wave-uniform base + lane*16 (HW)
__device__ __forceinline__ void gl_lds16(const void* g, void* l){
  __builtin_amdgcn_global_load_lds(
      (const __attribute__((address_space(1))) unsigned*)g,
      (__attribute__((address_space(3))) unsigned*)(unsigned)(unsigned long long)l,
      16, 0, 0);
}

// ---------- K0: fused x->bf16 convert (blocks 0..1023) + weight transposes ----------
__global__ void k_prep(const float* __restrict__ x, unsigned short* __restrict__ xb,
                       const float* __restrict__ Wq, unsigned short* __restrict__ Wqt,
                       const float* __restrict__ Wo, unsigned short* __restrict__ Wot){
  int bx = blockIdx.x;
  if (bx < 1024){                      // cvt: 8 elems/thread
    int i = bx * 256 + threadIdx.x;
    const float4* p = (const float4*)x + (size_t)i * 2;
    float4 a = p[0], b = p[1];
    uint4 o;
    o.x = pk(a.x, a.y); o.y = pk(a.z, a.w);
    o.z = pk(b.x, b.y); o.w = pk(b.z, b.w);
    ((uint4*)xb)[i] = o;
    return;
  }
  __shared__ float tile[32][33];
  int i = bx - 1024;                   // 0..767 -> (bxx 0..47, byy 0..15)
  int bxx = i % 48, byy = i / 48;
  const float* W; unsigned short* Wt; int N, n0;
  if (bxx < 32){ W = Wq; Wt = Wqt; N = 1024; n0 = bxx * 32; }
  else         { W = Wo; Wt = Wot; N = 512;  n0 = (bxx - 32) * 32; }
  int k0 = byy * 32;
  int tx = threadIdx.x & 31, ty = threadIdx.x >> 5;   // 32x8
  #pragma unroll
  for (int r = 0; r < 32; r += 8)
    tile[ty + r][tx] = W[(size_t)(k0 + ty + r) * N + n0 + tx];
  __syncthreads();
  #pragma unroll
  for (int r = 0; r < 32; r += 8)
    Wt[(size_t)(n0 + ty + r) * 512 + k0 + tx] = f2bf(tile[tx][ty + r]);
}

// ---------- K1/K4: bf16 MFMA GEMM, 2-phase dbuf global_load_lds ----------
// BM x 64 tile, BK=64, 4 waves (2x2; wave = BM/2 x 32). Linear LDS dest +
// inverse-swizzled global source + swizzled ds_read (rule #21).
// MODE 0 (BM=128): bn<8: silu*scale -> qb, tanh -> kb
//                  bn>=8: V-tile -> LDS transpose -> vt + vsum_p partials
// MODE 1 (BM=64) : yb = bf16(acc + bias + xb)
template<int MODE, int BM, int NBM, int NBN>
__launch_bounds__(256)
__global__ void k_gemm(const unsigned short* __restrict__ A,
                       const unsigned short* __restrict__ Bt,
                       const float* __restrict__ bias,
                       unsigned short* __restrict__ qb,
                       unsigned short* __restrict__ kb,
                       unsigned short* __restrict__ vt,
                       float* __restrict__ vsum_p,
                       const unsigned short* __restrict__ xb,
                       unsigned short* __restrict__ yb)
{
  const int K = 512;
  constexpr int NWG = NBM * NBN;
  constexpr int MF  = BM / 32;        // m-fragments per wave (4 or 2)
  __shared__ __align__(16) unsigned short ldsA[2][BM * 64];
  __shared__ __align__(16) unsigned short ldsB[2][64 * 64];
  int tid = threadIdx.x;
  int wid = tid >> 6, lane = tid & 63;
  int wm = wid >> 1, wn = wid & 1;
  int lane15 = lane & 15, laneh = lane >> 4;

  // XCD-aware bijective swizzle (NWG % 8 == 0)
  int g = blockIdx.x;
  int gwi = (g & 7) * (NWG / 8) + (g >> 3);
  int bm = gwi / NBN, bn = gwi % NBN;

  f32x4 acc[MF][2] = {};

  int srow_off = lane >> 3;           // 0..7
  int spos     = lane & 7;            // 0..7

  auto STAGE = [&](int buf, int kt){
    int k0 = kt * 64;
    #pragma unroll
    for (int c = 0; c < MF; ++c){     // A: BM/8 groups, MF per wave
      int cidx = wid * MF + c;
      int r = cidx * 8 + srow_off;
      int ch = spos ^ (r & 7);
      gl_lds16(A + (size_t)(bm * BM + r) * K + k0 + ch * 8, &ldsA[buf][cidx * 512]);
    }
    #pragma unroll
    for (int c = 0; c < 2; ++c){      // B: 8 groups, 2 per wave
      int cidx = wid * 2 + c;
      int r = cidx * 8 + srow_off;
      int ch = spos ^ (r & 7);
      gl_lds16(Bt + (size_t)(bn * 64 + r) * K + k0 + ch * 8, &ldsB[buf][cidx * 512]);
    }
  };

  auto COMPUTE = [&](int buf){
    #pragma unroll
    for (int kh = 0; kh < 2; ++kh){
      int chunk = kh * 4 + laneh;
      bf16x8 af[MF], bfv[2];
      #pragma unroll
      for (int mi = 0; mi < MF; ++mi){
        int row = wm * (BM / 2) + mi * 16 + lane15;
        af[mi] = *(const bf16x8*)&ldsA[buf][row * 64 + (chunk ^ (row & 7)) * 8];
      }
      #pragma unroll
      for (int ni = 0; ni < 2; ++ni){
        int row = wn * 32 + ni * 16 + lane15;
        bfv[ni] = *(const bf16x8*)&ldsB[buf][row * 64 + (chunk ^ (row & 7)) * 8];
      }
      #pragma unroll
      for (int mi = 0; mi < MF; ++mi)
        #pragma unroll
        for (int ni = 0; ni < 2; ++ni)
          acc[mi][ni] = __builtin_amdgcn_mfma_f32_16x16x32_bf16(af[mi], bfv[ni], acc[mi][ni], 0, 0, 0);
    }
  };

  STAGE(0, 0);
  __syncthreads();
  #pragma unroll
  for (int kt = 0; kt < 8; ++kt){
    if (kt < 7) STAGE((kt + 1) & 1, kt + 1);
    COMPUTE(kt & 1);
    __syncthreads();
  }

  if (MODE == 0 && bn >= 8){
    // ---- V path: transpose BM=128 x 64 tile in LDS, write vt + vsum partials ----
    unsigned short (*tp)[136] = (unsigned short (*)[136])&ldsA[0][0];  // 17.4 KB
    #pragma unroll
    for (int mi = 0; mi < MF; ++mi)
      #pragma unroll
      for (int ni = 0; ni < 2; ++ni)
        #pragma unroll
        for (int r = 0; r < 4; ++r){
          int ml = wm * (BM / 2) + mi * 16 + laneh * 4 + r;
          int nl = wn * 32 + ni * 16 + lane15;
          tp[nl][ml] = f2bf(acc[mi][ni][r] + bias[bn * 64 + nl]);
        }
    __syncthreads();
    int nl = tid >> 2, q = tid & 3;       // nl 0..63, q covers 32 m each
    int h = (bn - 8) * 2 + (nl >> 5), d = nl & 31;
    int b = bm >> 4, sc = bm & 15;        // 128-row s-chunk within batch
    int bh = b * 16 + h;
    uint4 v4[4];
    float ssum = 0.f;
    #pragma unroll
    for (int p = 0; p < 4; ++p){
      v4[p] = *(const uint4*)&tp[nl][q * 32 + p * 8];
      const unsigned* w = (const unsigned*)&v4[p];
      #pragma unroll
      for (int j = 0; j < 4; ++j){
        ssum += bf2f((unsigned short)(w[j] & 0xffff)) + bf2f((unsigned short)(w[j] >> 16));
      }
    }
    ssum += __shfl_xor(ssum, 1); ssum += __shfl_xor(ssum, 2);
    size_t vtoff = (size_t)(bh * HDIM + d) * SEQ + sc * 128 + q * 32;
    #pragma unroll
    for (int p = 0; p < 4; ++p) *(uint4*)(vt + vtoff + p * 8) = v4[p];
    if (q == 0) vsum_p[(sc * 32 + bh) * HDIM + d] = ssum;
  } else {
    #pragma unroll
    for (int mi = 0; mi < MF; ++mi){
      #pragma unroll
      for (int ni = 0; ni < 2; ++ni){
        #pragma unroll
        for (int r = 0; r < 4; ++r){
          int m = bm * BM + wm * (BM / 2) + mi * 16 + laneh * 4 + r;
          int n = bn * 64 + wn * 32 + ni * 16 + lane15;
          float val = acc[mi][ni][r] + bias[n];
          if (MODE == 0){
            float s = val / (1.0f + __expf(-val)) * QSCALE;  // silu * scale
            float t = tanhf(val);
            qb[(size_t)m * DIMX + n] = f2bf(s);
            kb[(size_t)m * DIMX + n] = f2bf(t);
          } else {
            size_t idx = (size_t)m * DIMX + n;
            yb[idx] = f2bf(val + bf2f(xb[idx]));
          }
        }
      }
    }
  }
}

// ---------- K3: banded attention (e^s - 1 trick), MFMA, 9 k-tiles ----------
__launch_bounds__(256)
__global__ void k_attn(const unsigned short* __restrict__ qb,
                       const unsigned short* __restrict__ kb,
                       const unsigned short* __restrict__ vt,
                       const float* __restrict__ vsum_p,
                       unsigned short* __restrict__ ao)
{
  __shared__ unsigned short p_lds[4][16][40];   // per-wave P staging, padded
  int tid = threadIdx.x, wid = tid >> 6, lane = tid & 63;
  int lane15 = lane & 15, laneh = lane >> 4;
  int bh = blockIdx.y, b = bh >> 4, h = bh & 15;
  int s0 = blockIdx.x * 64 + wid * 16;

  bf16x8 qf = *(const bf16x8*)(qb + (size_t)(b * SEQ + s0 + lane15) * DIMX + h * HDIM + laneh * 8);
  float vs0 = 0.f, vs1 = 0.f;
  #pragma unroll
  for (int c = 0; c < 16; ++c){
    vs0 += vsum_p[(c * 32 + bh) * HDIM + lane15];
    vs1 += vsum_p[(c * 32 + bh) * HDIM + 16 + lane15];
  }

  f32x4 accv[2] = {};
  float dsum[4] = {0.f, 0.f, 0.f, 0.f};

  // band |i-j|<=64 with i in [s0, s0+16) touches j in [s0-64, s0+80) = 9 tiles
  for (int jt = 0; jt < 9; ++jt){
    int j0 = s0 - 64 + jt * 16;
    int jc = min(max(j0 + lane15, 0), SEQ - 1);
    bf16x8 kf = *(const bf16x8*)(kb + (size_t)(b * SEQ + jc) * DIMX + h * HDIM + laneh * 8);
    f32x4 z = {0.f, 0.f, 0.f, 0.f};
    f32x4 sv = __builtin_amdgcn_mfma_f32_16x16x32_bf16(qf, kf, z, 0, 0, 0);
    #pragma unroll
    for (int r = 0; r < 4; ++r){
      int i = s0 + laneh * 4 + r;
      int j = j0 + lane15;
      int dj = i - j;
      bool inb = (dj <= WIN) && (dj >= -WIN) && (j >= 0) && (j < SEQ);
      float w = inb ? (__expf(sv[r]) - 1.0f) : 0.0f;
      dsum[r] += w;
      p_lds[wid][laneh * 4 + r][(jt & 1) * 16 + lane15] = f2bf(w);
    }
    if (jt & 1){
      int jc0 = j0 - 16;   // 32-wide chunk base
      bf16x8 pa = *(const bf16x8*)&p_lds[wid][lane15][laneh * 8];
      int jv = min(max(jc0 + laneh * 8, 0), SEQ - 8);
      bf16x8 v0 = *(const bf16x8*)(vt + (size_t)(bh * HDIM + lane15) * SEQ + jv);
      bf16x8 v1 = *(const bf16x8*)(vt + (size_t)(bh * HDIM + 16 + lane15) * SEQ + jv);
      accv[0] = __builtin_amdgcn_mfma_f32_16x16x32_bf16(pa, v0, accv[0], 0, 0, 0);
      accv[1] = __builtin_amdgcn_mfma_f32_16x16x32_bf16(pa, v1, accv[1], 0, 0, 0);
    }
  }
  // tail PV for tile 8 (cols 0..15); zero cols 16..31 first
  {
    #pragma unroll
    for (int r = 0; r < 4; ++r)
      p_lds[wid][laneh * 4 + r][16 + lane15] = 0;
    int jc0 = s0 + 64;
    bf16x8 pa = *(const bf16x8*)&p_lds[wid][lane15][laneh * 8];
    int jv = min(max(jc0 + laneh * 8, 0), SEQ - 8);
    bf16x8 v0 = *(const bf16x8*)(vt + (size_t)(bh * HDIM + lane15) * SEQ + jv);
    bf16x8 v1 = *(const bf16x8*)(vt + (size_t)(bh * HDIM + 16 + lane15) * SEQ + jv);
    accv[0] = __builtin_amdgcn_mfma_f32_16x16x32_bf16(pa, v0, accv[0], 0, 0, 0);
    accv[1] = __builtin_amdgcn_mfma_f32_16x16x32_bf16(pa, v1, accv[1], 0, 0, 0);
  }

  #pragma unroll
  for (int r = 0; r < 4; ++r){
    float v = dsum[r];
    v += __shfl_xor(v, 1); v += __shfl_xor(v, 2);
    v += __shfl_xor(v, 4); v += __shfl_xor(v, 8);
    dsum[r] = v;
  }
  #pragma unroll
  for (int r = 0; r < 4; ++r){
    int i = s0 + laneh * 4 + r;
    float dn = (float)SEQ + dsum[r];
    float o0 = (accv[0][r] + vs0) / dn;
    float o1 = (accv[1][r] + vs1) / dn;
    size_t base = (size_t)(b * SEQ + i) * DIMX + h * HDIM;
    ao[base + lane15]      = f2bf(o0);
    ao[base + 16 + lane15] = f2bf(o1);
  }
}

// ---------- K5: LayerNorm over 512 (bf16 in, fp32 out), one wave per row ----------
__global__ void k_ln(const unsigned short* __restrict__ yb, const float* __restrict__ gamma,
                     const float* __restrict__ beta, float* __restrict__ out){
  int wid = threadIdx.x >> 6, lane = threadIdx.x & 63;
  int row = blockIdx.x * 4 + wid;
  uint4 u = *(const uint4*)(yb + (size_t)row * DIMX + lane * 8);
  const unsigned* w = (const unsigned*)&u;
  float v[8];
  #pragma unroll
  for (int j = 0; j < 4; ++j){
    v[2*j]   = bf2f((unsigned short)(w[j] & 0xffff));
    v[2*j+1] = bf2f((unsigned short)(w[j] >> 16));
  }
  float s = 0.f, ss = 0.f;
  #pragma unroll
  for (int j = 0; j < 8; ++j){ s += v[j]; ss += v[j] * v[j]; }
  #pragma unroll
  for (int m = 1; m < 64; m <<= 1){ s += __shfl_xor(s, m); ss += __shfl_xor(ss, m); }
  float mu = s * (1.f / DIMX);
  float var = ss * (1.f / DIMX) - mu * mu;
  float inv = rsqrtf(var + 1e-5f);
  float4 g0 = *(const float4*)(gamma + lane * 8);
  float4 g1 = *(const float4*)(gamma + lane * 8 + 4);
  float4 b0 = *(const float4*)(beta + lane * 8);
  float4 b1 = *(const float4*)(beta + lane * 8 + 4);
  float4 o0, o1;
  o0.x = (v[0] - mu) * inv * g0.x + b0.x; o0.y = (v[1] - mu) * inv * g0.y + b0.y;
  o0.z = (v[2] - mu) * inv * g0.z + b0.z; o0.w = (v[3] - mu) * inv * g0.w + b0.w;
  o1.x = (v[4] - mu) * inv * g1.x + b1.x; o1.y = (v[5] - mu) * inv * g1.y + b1.y;
  o1.z = (v[6] - mu) * inv * g1.z + b1.z; o1.w = (v[7] - mu) * inv * g1.w + b1.w;
  float* op = out + (size_t)row * DIMX + lane * 8;
  *(float4*)op = o0; *(float4*)(op + 4) = o1;
}

extern "C" void kernel_launch(void* const* d_in, const int* in_sizes, int n_in,
                              void* d_out, int out_size, void* d_ws, size_t ws_size,
                              hipStream_t stream){
  const float* x      = (const float*)d_in[0];
  const float* W_qkv  = (const float*)d_in[1];
  const float* b_qkv  = (const float*)d_in[2];
  const float* W_out  = (const float*)d_in[3];
  const float* b_out  = (const float*)d_in[4];
  const float* gamma  = (const float*)d_in[5];
  const float* beta   = (const float*)d_in[6];
  float* out = (float*)d_out;

  char* ws = (char*)d_ws;
  size_t off = 0;
  auto alloc = [&](size_t bytes){ void* p = ws + off; off += (bytes + 255) & ~(size_t)255; return p; };
  unsigned short* xb  = (unsigned short*)alloc((size_t)MTOT * DIMX * 2);
  unsigned short* wqt = (unsigned short*)alloc((size_t)1024 * 512 * 2);
  unsigned short* wot = (unsigned short*)alloc((size_t)512 * 512 * 2);
  unsigned short* qb  = (unsigned short*)alloc((size_t)MTOT * DIMX * 2);
  unsigned short* kb  = (unsigned short*)alloc((size_t)MTOT * DIMX * 2);
  unsigned short* vt  = (unsigned short*)alloc((size_t)32 * HDIM * SEQ * 2);
  float*          vsm = (float*)alloc((size_t)16 * 32 * HDIM * 4);
  unsigned short* ao  = (unsigned short*)alloc((size_t)MTOT * DIMX * 2);
  unsigned short* yb  = (unsigned short*)alloc((size_t)MTOT * DIMX * 2);

  k_prep<<<1792, 256, 0, stream>>>(x, xb, W_qkv, wqt, W_out, wot);
  k_gemm<0, 128, 32, 16><<<512, 256, 0, stream>>>(xb, wqt, b_qkv, qb, kb, vt, vsm, nullptr, nullptr);
  k_attn<<<dim3(32, 32), 256, 0, stream>>>(qb, kb, vt, vsm, ao);
  k_gemm<1, 64, 64, 8><<<512, 256, 0, stream>>>(ao, wot, b_out, nullptr, nullptr, nullptr, nullptr, xb, yb);
  k_ln  <<<MTOT / 4, 256, 0, stream>>>(yb, gamma, beta, out);
}

// Round 8
// 46.065 us; speedup vs baseline: 3.9360x; 1.0611x over previous
//
#include <hip/hip_runtime.h>
#include <cstdint>
#include <cstddef>

#define DIMX 512
#define HDIM 32
#define NHEADS 16
#define SEQ 2048
#define BATCH 2
#define MTOT (BATCH*SEQ)   // 4096
#define WIN 64
#define QSCALE 0.17677669529663687f  // 32^-0.5

typedef __bf16 bf16x8 __attribute__((ext_vector_type(8)));
typedef float f32x4 __attribute__((ext_vector_type(4)));

__device__ __forceinline__ unsigned short f2bf(float f){
  unsigned u = __builtin_bit_cast(unsigned, f);
  u += 0x7FFFu + ((u >> 16) & 1u);          // RNE
  return (unsigned short)(u >> 16);
}
__device__ __forceinline__ float bf2f(unsigned short s){
  return __builtin_bit_cast(float, ((unsigned)s) << 16);
}
__device__ __forceinline__ unsigned pk(float a, float b){
  return (unsigned)f2bf(a) | ((unsigned)f2bf(b) << 16);
}

// async global->LDS, 16B per lane; dest is wave-uniform base + lane*16 (HW)
__device__ __forceinline__ void gl_lds16(const void* g, void* l){
  __builtin_amdgcn_global_load_lds(
      (const __attribute__((address_space(1))) unsigned*)g,
      (__attribute__((address_space(3))) unsigned*)(unsigned)(unsigned long long)l,
      16, 0, 0);
}

template<int N> __device__ __forceinline__ void vmwait(){
  if      constexpr (N == 12) asm volatile("s_waitcnt vmcnt(12)" ::: "memory");
  else if constexpr (N ==  8) asm volatile("s_waitcnt vmcnt(8)"  ::: "memory");
  else if constexpr (N ==  6) asm volatile("s_waitcnt vmcnt(6)"  ::: "memory");
  else if constexpr (N ==  4) asm volatile("s_waitcnt vmcnt(4)"  ::: "memory");
  else                        asm volatile("s_waitcnt vmcnt(0)"  ::: "memory");
}

// ---------- K0: fused x->bf16 convert (blocks 0..1023) + weight transposes ----------
__global__ void k_prep(const float* __restrict__ x, unsigned short* __restrict__ xb,
                       const float* __restrict__ Wq, unsigned short* __restrict__ Wqt,
                       const float* __restrict__ Wo, unsigned short* __restrict__ Wot){
  int bx = blockIdx.x;
  if (bx < 1024){                      // cvt: 8 elems/thread
    int i = bx * 256 + threadIdx.x;
    const float4* p = (const float4*)x + (size_t)i * 2;
    float4 a = p[0], b = p[1];
    uint4 o;
    o.x = pk(a.x, a.y); o.y = pk(a.z, a.w);
    o.z = pk(b.x, b.y); o.w = pk(b.z, b.w);
    ((uint4*)xb)[i] = o;
    return;
  }
  __shared__ float tile[32][33];
  int i = bx - 1024;                   // 0..767 -> (bxx 0..47, byy 0..15)
  int bxx = i % 48, byy = i / 48;
  const float* W; unsigned short* Wt; int N, n0;
  if (bxx < 32){ W = Wq; Wt = Wqt; N = 1024; n0 = bxx * 32; }
  else         { W = Wo; Wt = Wot; N = 512;  n0 = (bxx - 32) * 32; }
  int k0 = byy * 32;
  int tx = threadIdx.x & 31, ty = threadIdx.x >> 5;   // 32x8
  #pragma unroll
  for (int r = 0; r < 32; r += 8)
    tile[ty + r][tx] = W[(size_t)(k0 + ty + r) * N + n0 + tx];
  __syncthreads();
  #pragma unroll
  for (int r = 0; r < 32; r += 8)
    Wt[(size_t)(n0 + ty + r) * 512 + k0 + tx] = f2bf(tile[tx][ty + r]);
}

// ---------- K1/K4: bf16 MFMA GEMM, 3-buffer depth-2 pipeline, counted vmcnt ----------
// BM x 64 tile, BK=64, 4 waves (2x2; wave = BM/2 x 32). Linear LDS dest +
// inverse-swizzled global source + swizzled ds_read (rule #21).
// Two raw s_barriers per K-step; loads for steps kt+1,kt+2 stay in flight (T4).
// MODE 0 (BM=128): bn<8: silu*scale -> qb, tanh -> kb
//                  bn>=8: V-tile -> LDS transpose -> vt + vsum_p partials
// MODE 1 (BM=64) : yb = bf16(acc + bias + xb)
template<int MODE, int BM, int NBM, int NBN>
__launch_bounds__(256)
__global__ void k_gemm(const unsigned short* __restrict__ A,
                       const unsigned short* __restrict__ Bt,
                       const float* __restrict__ bias,
                       unsigned short* __restrict__ qb,
                       unsigned short* __restrict__ kb,
                       unsigned short* __restrict__ vt,
                       float* __restrict__ vsum_p,
                       const unsigned short* __restrict__ xb,
                       unsigned short* __restrict__ yb)
{
  const int K = 512;
  constexpr int NWG = NBM * NBN;
  constexpr int MF  = BM / 32;        // m-fragments per wave (4 or 2)
  constexpr int LPS = MF + 2;         // gl_lds issued per thread per K-step
  __shared__ __align__(16) unsigned short ldsA[3][BM * 64];
  __shared__ __align__(16) unsigned short ldsB[3][64 * 64];
  int tid = threadIdx.x;
  int wid = tid >> 6, lane = tid & 63;
  int wm = wid >> 1, wn = wid & 1;
  int lane15 = lane & 15, laneh = lane >> 4;

  // XCD-aware bijective swizzle (NWG % 8 == 0)
  int g = blockIdx.x;
  int gwi = (g & 7) * (NWG / 8) + (g >> 3);
  int bm = gwi / NBN, bn = gwi % NBN;

  f32x4 acc[MF][2] = {};

  int srow_off = lane >> 3;           // 0..7
  int spos     = lane & 7;            // 0..7

  auto STAGE = [&](int buf, int kt){
    int k0 = kt * 64;
    #pragma unroll
    for (int c = 0; c < MF; ++c){     // A: BM/8 groups, MF per wave
      int cidx = wid * MF + c;
      int r = cidx * 8 + srow_off;
      int ch = spos ^ (r & 7);
      gl_lds16(A + (size_t)(bm * BM + r) * K + k0 + ch * 8, &ldsA[buf][cidx * 512]);
    }
    #pragma unroll
    for (int c = 0; c < 2; ++c){      // B: 8 groups, 2 per wave
      int cidx = wid * 2 + c;
      int r = cidx * 8 + srow_off;
      int ch = spos ^ (r & 7);
      gl_lds16(Bt + (size_t)(bn * 64 + r) * K + k0 + ch * 8, &ldsB[buf][cidx * 512]);
    }
  };

  auto COMPUTE = [&](int buf){
    #pragma unroll
    for (int kh = 0; kh < 2; ++kh){
      int chunk = kh * 4 + laneh;
      bf16x8 af[MF], bfv[2];
      #pragma unroll
      for (int mi = 0; mi < MF; ++mi){
        int row = wm * (BM / 2) + mi * 16 + lane15;
        af[mi] = *(const bf16x8*)&ldsA[buf][row * 64 + (chunk ^ (row & 7)) * 8];
      }
      #pragma unroll
      for (int ni = 0; ni < 2; ++ni){
        int row = wn * 32 + ni * 16 + lane15;
        bfv[ni] = *(const bf16x8*)&ldsB[buf][row * 64 + (chunk ^ (row & 7)) * 8];
      }
      #pragma unroll
      for (int mi = 0; mi < MF; ++mi)
        #pragma unroll
        for (int ni = 0; ni < 2; ++ni)
          acc[mi][ni] = __builtin_amdgcn_mfma_f32_16x16x32_bf16(af[mi], bfv[ni], acc[mi][ni], 0, 0, 0);
    }
  };

  // 3-buffer, depth-2 prefetch; two raw barriers per step, counted vmcnt.
  STAGE(0, 0);
  STAGE(1, 1);
  #pragma unroll
  for (int kt = 0; kt < 8; ++kt){
    if (kt < 6) STAGE((kt + 2) % 3, kt + 2);
    if (kt < 6)       vmwait<2 * LPS>();   // step-kt loads (oldest LPS) done
    else if (kt == 6) vmwait<LPS>();
    else              vmwait<0>();
    __builtin_amdgcn_s_barrier();          // all waves: buf kt fully staged
    __builtin_amdgcn_sched_barrier(0);
    COMPUTE(kt % 3);
    __builtin_amdgcn_s_barrier();          // all waves done reading buf kt
    __builtin_amdgcn_sched_barrier(0);
  }

  if (MODE == 0 && bn >= 8){
    // ---- V path: transpose BM=128 x 64 tile in LDS, write vt + vsum partials ----
    unsigned short (*tp)[136] = (unsigned short (*)[136])&ldsA[0][0];  // 17.4 KB
    #pragma unroll
    for (int mi = 0; mi < MF; ++mi)
      #pragma unroll
      for (int ni = 0; ni < 2; ++ni)
        #pragma unroll
        for (int r = 0; r < 4; ++r){
          int ml = wm * (BM / 2) + mi * 16 + laneh * 4 + r;
          int nl = wn * 32 + ni * 16 + lane15;
          tp[nl][ml] = f2bf(acc[mi][ni][r] + bias[bn * 64 + nl]);
        }
    __syncthreads();
    int nl = tid >> 2, q = tid & 3;       // nl 0..63, q covers 32 m each
    int h = (bn - 8) * 2 + (nl >> 5), d = nl & 31;
    int b = bm >> 4, sc = bm & 15;        // 128-row s-chunk within batch
    int bh = b * 16 + h;
    uint4 v4[4];
    float ssum = 0.f;
    #pragma unroll
    for (int p = 0; p < 4; ++p){
      v4[p] = *(const uint4*)&tp[nl][q * 32 + p * 8];
      const unsigned* w = (const unsigned*)&v4[p];
      #pragma unroll
      for (int j = 0; j < 4; ++j){
        ssum += bf2f((unsigned short)(w[j] & 0xffff)) + bf2f((unsigned short)(w[j] >> 16));
      }
    }
    ssum += __shfl_xor(ssum, 1); ssum += __shfl_xor(ssum, 2);
    size_t vtoff = (size_t)(bh * HDIM + d) * SEQ + sc * 128 + q * 32;
    #pragma unroll
    for (int p = 0; p < 4; ++p) *(uint4*)(vt + vtoff + p * 8) = v4[p];
    if (q == 0) vsum_p[(sc * 32 + bh) * HDIM + d] = ssum;
  } else {
    #pragma unroll
    for (int mi = 0; mi < MF; ++mi){
      #pragma unroll
      for (int ni = 0; ni < 2; ++ni){
        #pragma unroll
        for (int r = 0; r < 4; ++r){
          int m = bm * BM + wm * (BM / 2) + mi * 16 + laneh * 4 + r;
          int n = bn * 64 + wn * 32 + ni * 16 + lane15;
          float val = acc[mi][ni][r] + bias[n];
          if (MODE == 0){
            float s = val / (1.0f + __expf(-val)) * QSCALE;      // silu * scale
            float t = 1.0f - 2.0f / (1.0f + __expf(2.0f * val)); // tanh, no libcall
            qb[(size_t)m * DIMX + n] = f2bf(s);
            kb[(size_t)m * DIMX + n] = f2bf(t);
          } else {
            size_t idx = (size_t)m * DIMX + n;
            yb[idx] = f2bf(val + bf2f(xb[idx]));
          }
        }
      }
    }
  }
}

// ---------- K3: banded attention (e^s - 1 trick), MFMA, 9 k-tiles ----------
__launch_bounds__(256)
__global__ void k_attn(const unsigned short* __restrict__ qb,
                       const unsigned short* __restrict__ kb,
                       const unsigned short* __restrict__ vt,
                       const float* __restrict__ vsum_p,
                       unsigned short* __restrict__ ao)
{
  __shared__ unsigned short p_lds[4][16][40];   // per-wave P staging, padded
  int tid = threadIdx.x, wid = tid >> 6, lane = tid & 63;
  int lane15 = lane & 15, laneh = lane >> 4;
  int bh = blockIdx.y, b = bh >> 4, h = bh & 15;
  int s0 = blockIdx.x * 64 + wid * 16;

  bf16x8 qf = *(const bf16x8*)(qb + (size_t)(b * SEQ + s0 + lane15) * DIMX + h * HDIM + laneh * 8);
  float vs0 = 0.f, vs1 = 0.f;
  #pragma unroll
  for (int c = 0; c < 16; ++c){
    vs0 += vsum_p[(c * 32 + bh) * HDIM + lane15];
    vs1 += vsum_p[(c * 32 + bh) * HDIM + 16 + lane15];
  }

  f32x4 accv[2] = {};
  float dsum[4] = {0.f, 0.f, 0.f, 0.f};

  // band |i-j|<=64 with i in [s0, s0+16) touches j in [s0-64, s0+80) = 9 tiles
  for (int jt = 0; jt < 9; ++jt){
    int j0 = s0 - 64 + jt * 16;
    int jc = min(max(j0 + lane15, 0), SEQ - 1);
    bf16x8 kf = *(const bf16x8*)(kb + (size_t)(b * SEQ + jc) * DIMX + h * HDIM + laneh * 8);
    f32x4 z = {0.f, 0.f, 0.f, 0.f};
    f32x4 sv = __builtin_amdgcn_mfma_f32_16x16x32_bf16(qf, kf, z, 0, 0, 0);
    #pragma unroll
    for (int r = 0; r < 4; ++r){
      int i = s0 + laneh * 4 + r;
      int j = j0 + lane15;
      int dj = i - j;
      bool inb = (dj <= WIN) && (dj >= -WIN) && (j >= 0) && (j < SEQ);
      float w = inb ? (__expf(sv[r]) - 1.0f) : 0.0f;
      dsum[r] += w;
      p_lds[wid][laneh * 4 + r][(jt & 1) * 16 + lane15] = f2bf(w);
    }
    if (jt & 1){
      int jc0 = j0 - 16;   // 32-wide chunk base
      bf16x8 pa = *(const bf16x8*)&p_lds[wid][lane15][laneh * 8];
      int jv = min(max(jc0 + laneh * 8, 0), SEQ - 8);
      bf16x8 v0 = *(const bf16x8*)(vt + (size_t)(bh * HDIM + lane15) * SEQ + jv);
      bf16x8 v1 = *(const bf16x8*)(vt + (size_t)(bh * HDIM + 16 + lane15) * SEQ + jv);
      accv[0] = __builtin_amdgcn_mfma_f32_16x16x32_bf16(pa, v0, accv[0], 0, 0, 0);
      accv[1] = __builtin_amdgcn_mfma_f32_16x16x32_bf16(pa, v1, accv[1], 0, 0, 0);
    }
  }
  // tail PV for tile 8 (cols 0..15); zero cols 16..31 first
  {
    #pragma unroll
    for (int r = 0; r < 4; ++r)
      p_lds[wid][laneh * 4 + r][16 + lane15] = 0;
    int jc0 = s0 + 64;
    bf16x8 pa = *(const bf16x8*)&p_lds[wid][lane15][laneh * 8];
    int jv = min(max(jc0 + laneh * 8, 0), SEQ - 8);
    bf16x8 v0 = *(const bf16x8*)(vt + (size_t)(bh * HDIM + lane15) * SEQ + jv);
    bf16x8 v1 = *(const bf16x8*)(vt + (size_t)(bh * HDIM + 16 + lane15) * SEQ + jv);
    accv[0] = __builtin_amdgcn_mfma_f32_16x16x32_bf16(pa, v0, accv[0], 0, 0, 0);
    accv[1] = __builtin_amdgcn_mfma_f32_16x16x32_bf16(pa, v1, accv[1], 0, 0, 0);
  }

  #pragma unroll
  for (int r = 0; r < 4; ++r){
    float v = dsum[r];
    v += __shfl_xor(v, 1); v += __shfl_xor(v, 2);
    v += __shfl_xor(v, 4); v += __shfl_xor(v, 8);
    dsum[r] = v;
  }
  #pragma unroll
  for (int r = 0; r < 4; ++r){
    int i = s0 + laneh * 4 + r;
    float dn = (float)SEQ + dsum[r];
    float o0 = (accv[0][r] + vs0) / dn;
    float o1 = (accv[1][r] + vs1) / dn;
    size_t base = (size_t)(b * SEQ + i) * DIMX + h * HDIM;
    ao[base + lane15]      = f2bf(o0);
    ao[base + 16 + lane15] = f2bf(o1);
  }
}

// ---------- K5: LayerNorm over 512 (bf16 in, fp32 out), one wave per row ----------
__global__ void k_ln(const unsigned short* __restrict__ yb, const float* __restrict__ gamma,
                     const float* __restrict__ beta, float* __restrict__ out){
  int wid = threadIdx.x >> 6, lane = threadIdx.x & 63;
  int row = blockIdx.x * 4 + wid;
  uint4 u = *(const uint4*)(yb + (size_t)row * DIMX + lane * 8);
  const unsigned* w = (const unsigned*)&u;
  float v[8];
  #pragma unroll
  for (int j = 0; j < 4; ++j){
    v[2*j]   = bf2f((unsigned short)(w[j] & 0xffff));
    v[2*j+1] = bf2f((unsigned short)(w[j] >> 16));
  }
  float s = 0.f, ss = 0.f;
  #pragma unroll
  for (int j = 0; j < 8; ++j){ s += v[j]; ss += v[j] * v[j]; }
  #pragma unroll
  for (int m = 1; m < 64; m <<= 1){ s += __shfl_xor(s, m); ss += __shfl_xor(ss, m); }
  float mu = s * (1.f / DIMX);
  float var = ss * (1.f / DIMX) - mu * mu;
  float inv = rsqrtf(var + 1e-5f);
  float4 g0 = *(const float4*)(gamma + lane * 8);
  float4 g1 = *(const float4*)(gamma + lane * 8 + 4);
  float4 b0 = *(const float4*)(beta + lane * 8);
  float4 b1 = *(const float4*)(beta + lane * 8 + 4);
  float4 o0, o1;
  o0.x = (v[0] - mu) * inv * g0.x + b0.x; o0.y = (v[1] - mu) * inv * g0.y + b0.y;
  o0.z = (v[2] - mu) * inv * g0.z + b0.z; o0.w = (v[3] - mu) * inv * g0.w + b0.w;
  o1.x = (v[4] - mu) * inv * g1.x + b1.x; o1.y = (v[5] - mu) * inv * g1.y + b1.y;
  o1.z = (v[6] - mu) * inv * g1.z + b1.z; o1.w = (v[7] - mu) * inv * g1.w + b1.w;
  float* op = out + (size_t)row * DIMX + lane * 8;
  *(float4*)op = o0; *(float4*)(op + 4) = o1;
}

extern "C" void kernel_launch(void* const* d_in, const int* in_sizes, int n_in,
                              void* d_out, int out_size, void* d_ws, size_t ws_size,
                              hipStream_t stream){
  const float* x      = (const float*)d_in[0];
  const float* W_qkv  = (const float*)d_in[1];
  const float* b_qkv  = (const float*)d_in[2];
  const float* W_out  = (const float*)d_in[3];
  const float* b_out  = (const float*)d_in[4];
  const float* gamma  = (const float*)d_in[5];
  const float* beta   = (const float*)d_in[6];
  float* out = (float*)d_out;

  char* ws = (char*)d_ws;
  size_t off = 0;
  auto alloc = [&](size_t bytes){ void* p = ws + off; off += (bytes + 255) & ~(size_t)255; return p; };
  unsigned short* xb  = (unsigned short*)alloc((size_t)MTOT * DIMX * 2);
  unsigned short* wqt = (unsigned short*)alloc((size_t)1024 * 512 * 2);
  unsigned short* wot = (unsigned short*)alloc((size_t)512 * 512 * 2);
  unsigned short* qb  = (unsigned short*)alloc((size_t)MTOT * DIMX * 2);
  unsigned short* kb  = (unsigned short*)alloc((size_t)MTOT * DIMX * 2);
  unsigned short* vt  = (unsigned short*)alloc((size_t)32 * HDIM * SEQ * 2);
  float*          vsm = (float*)alloc((size_t)16 * 32 * HDIM * 4);
  unsigned short* ao  = (unsigned short*)alloc((size_t)MTOT * DIMX * 2);
  unsigned short* yb  = (unsigned short*)alloc((size_t)MTOT * DIMX * 2);

  k_prep<<<1792, 256, 0, stream>>>(x, xb, W_qkv, wqt, W_out, wot);
  k_gemm<0, 128, 32, 16><<<512, 256, 0, stream>>>(xb, wqt, b_qkv, qb, kb, vt, vsm, nullptr, nullptr);
  k_attn<<<dim3(32, 32), 256, 0, stream>>>(qb, kb, vt, vsm, ao);
  k_gemm<1, 64, 64, 8><<<512, 256, 0, stream>>>(ao, wot, b_out, nullptr, nullptr, nullptr, nullptr, xb, yb);
  k_ln  <<<MTOT / 4, 256, 0, stream>>>(yb, gamma, beta, out);
}

// Round 9
// 45.032 us; speedup vs baseline: 4.0263x; 1.0229x over previous
//
#include <hip/hip_runtime.h>
#include <cstdint>
#include <cstddef>

#define DIMX 512
#define HDIM 32
#define NHEADS 16
#define SEQ 2048
#define BATCH 2
#define MTOT (BATCH*SEQ)   // 4096
#define WIN 64
#define QSCALE 0.17677669529663687f  // 32^-0.5

typedef __bf16 bf16x8 __attribute__((ext_vector_type(8)));
typedef float f32x4 __attribute__((ext_vector_type(4)));

__device__ __forceinline__ unsigned short f2bf(float f){
  unsigned u = __builtin_bit_cast(unsigned, f);
  u += 0x7FFFu + ((u >> 16) & 1u);          // RNE
  return (unsigned short)(u >> 16);
}
__device__ __forceinline__ float bf2f(unsigned short s){
  return __builtin_bit_cast(float, ((unsigned)s) << 16);
}
__device__ __forceinline__ unsigned pk(float a, float b){
  return (unsigned)f2bf(a) | ((unsigned)f2bf(b) << 16);
}

// async global->LDS, 16B per lane; dest is wave-uniform base + lane*16 (HW)
__device__ __forceinline__ void gl_lds16(const void* g, void* l){
  __builtin_amdgcn_global_load_lds(
      (const __attribute__((address_space(1))) unsigned*)g,
      (__attribute__((address_space(3))) unsigned*)(unsigned)(unsigned long long)l,
      16, 0, 0);
}

template<int N> __device__ __forceinline__ void vmwait(){
  if      constexpr (N ==  8) asm volatile("s_waitcnt vmcnt(8)"  ::: "memory");
  else if constexpr (N ==  4) asm volatile("s_waitcnt vmcnt(4)"  ::: "memory");
  else                        asm volatile("s_waitcnt vmcnt(0)"  ::: "memory");
}

// ---------- K0: fused x->bf16 convert (blocks 0..1023) + weight transposes ----------
__global__ void k_prep(const float* __restrict__ x, unsigned short* __restrict__ xb,
                       const float* __restrict__ Wq, unsigned short* __restrict__ Wqt,
                       const float* __restrict__ Wo, unsigned short* __restrict__ Wot){
  int bx = blockIdx.x;
  if (bx < 1024){                      // cvt: 8 elems/thread
    int i = bx * 256 + threadIdx.x;
    const float4* p = (const float4*)x + (size_t)i * 2;
    float4 a = p[0], b = p[1];
    uint4 o;
    o.x = pk(a.x, a.y); o.y = pk(a.z, a.w);
    o.z = pk(b.x, b.y); o.w = pk(b.z, b.w);
    ((uint4*)xb)[i] = o;
    return;
  }
  __shared__ float tile[32][33];
  int i = bx - 1024;                   // 0..767 -> (bxx 0..47, byy 0..15)
  int bxx = i % 48, byy = i / 48;
  const float* W; unsigned short* Wt; int N, n0;
  if (bxx < 32){ W = Wq; Wt = Wqt; N = 1024; n0 = bxx * 32; }
  else         { W = Wo; Wt = Wot; N = 512;  n0 = (bxx - 32) * 32; }
  int k0 = byy * 32;
  int tx = threadIdx.x & 31, ty = threadIdx.x >> 5;   // 32x8
  #pragma unroll
  for (int r = 0; r < 32; r += 8)
    tile[ty + r][tx] = W[(size_t)(k0 + ty + r) * N + n0 + tx];
  __syncthreads();
  #pragma unroll
  for (int r = 0; r < 32; r += 8)
    Wt[(size_t)(n0 + ty + r) * 512 + k0 + tx] = f2bf(tile[tx][ty + r]);
}

// ---------- K1/K4: bf16 MFMA GEMM, 2-buf depth-1 counted-vmcnt pipeline ----------
// BM x BN block, BK=64, 4 waves (2x2; wave = BM/2 x BN/2). Linear LDS dest +
// inverse-swizzled global source + swizzled ds_read (rule #21).
// MODE 0 (128x128): bn<4: q=silu*scale, k=tanh -> HEAD-MAJOR [bh][s][32]
//                   bn>=4: V-tile -> LDS transpose -> vt[bh*32+d][s] + vsum_p
// MODE 1 (64x64)  : yb = bf16(acc + bias + xb)
template<int MODE, int BM, int BN, int NBN>
__launch_bounds__(256)
__global__ void k_gemm(const unsigned short* __restrict__ A,
                       const unsigned short* __restrict__ Bt,
                       const float* __restrict__ bias,
                       unsigned short* __restrict__ qb,
                       unsigned short* __restrict__ kb,
                       unsigned short* __restrict__ vt,
                       float* __restrict__ vsum_p,
                       const unsigned short* __restrict__ xb,
                       unsigned short* __restrict__ yb)
{
  const int K = 512;
  constexpr int NWG = (MTOT / BM) * NBN;
  constexpr int MF  = BM / 32, NF = BN / 32;   // frags per wave
  constexpr int LPS = (BM + BN) / 32;          // gl_lds per thread per K-step
  __shared__ __align__(16) unsigned short lds[2][(BM + BN) * 64];
  int tid = threadIdx.x;
  int wid = tid >> 6, lane = tid & 63;
  int wm = wid >> 1, wn = wid & 1;
  int lane15 = lane & 15, laneh = lane >> 4;

  // XCD-aware bijective swizzle (NWG % 8 == 0)
  int g = blockIdx.x;
  int gwi = (g & 7) * (NWG / 8) + (g >> 3);
  int bm = gwi / NBN, bn = gwi % NBN;

  f32x4 acc[MF][NF] = {};

  int srow_off = lane >> 3;           // 0..7
  int spos     = lane & 7;            // 0..7

  auto STAGE = [&](int buf, int kt){
    int k0 = kt * 64;
    #pragma unroll
    for (int c = 0; c < MF; ++c){     // A: BM/8 groups, MF per wave
      int cidx = wid * MF + c;
      int r = cidx * 8 + srow_off;
      int ch = spos ^ (r & 7);
      gl_lds16(A + (size_t)(bm * BM + r) * K + k0 + ch * 8, &lds[buf][cidx * 512]);
    }
    #pragma unroll
    for (int c = 0; c < NF; ++c){     // B: BN/8 groups, NF per wave
      int cidx = wid * NF + c;
      int r = cidx * 8 + srow_off;
      int ch = spos ^ (r & 7);
      gl_lds16(Bt + (size_t)(bn * BN + r) * K + k0 + ch * 8, &lds[buf][BM * 64 + cidx * 512]);
    }
  };

  auto COMPUTE = [&](int buf){
    #pragma unroll
    for (int kh = 0; kh < 2; ++kh){
      int chunk = kh * 4 + laneh;
      bf16x8 af[MF], bfv[NF];
      #pragma unroll
      for (int mi = 0; mi < MF; ++mi){
        int row = wm * (BM / 2) + mi * 16 + lane15;
        af[mi] = *(const bf16x8*)&lds[buf][row * 64 + (chunk ^ (row & 7)) * 8];
      }
      #pragma unroll
      for (int ni = 0; ni < NF; ++ni){
        int row = wn * (BN / 2) + ni * 16 + lane15;
        bfv[ni] = *(const bf16x8*)&lds[buf][BM * 64 + row * 64 + (chunk ^ (row & 7)) * 8];
      }
      #pragma unroll
      for (int mi = 0; mi < MF; ++mi)
        #pragma unroll
        for (int ni = 0; ni < NF; ++ni)
          acc[mi][ni] = __builtin_amdgcn_mfma_f32_16x16x32_bf16(af[mi], bfv[ni], acc[mi][ni], 0, 0, 0);
    }
  };

  // 2-buffer, depth-1 prefetch; counted vmcnt keeps next tile's loads in flight.
  STAGE(0, 0);
  #pragma unroll
  for (int kt = 0; kt < 8; ++kt){
    if (kt < 7) STAGE((kt + 1) & 1, kt + 1);
    if (kt < 7) vmwait<LPS>(); else vmwait<0>();
    __builtin_amdgcn_s_barrier();          // buf kt fully staged for all waves
    __builtin_amdgcn_sched_barrier(0);
    COMPUTE(kt & 1);
    __builtin_amdgcn_s_barrier();          // all waves done reading buf kt
    __builtin_amdgcn_sched_barrier(0);
  }

  if (MODE == 0 && bn >= 4){
    // ---- V path: transpose 128x128 tile in LDS, write vt + vsum partials ----
    unsigned short (*tp)[136] = (unsigned short (*)[136])&lds[0][0];  // 34.8 KB
    #pragma unroll
    for (int mi = 0; mi < MF; ++mi)
      #pragma unroll
      for (int ni = 0; ni < NF; ++ni)
        #pragma unroll
        for (int r = 0; r < 4; ++r){
          int ml = wm * (BM / 2) + mi * 16 + laneh * 4 + r;
          int nl = wn * (BN / 2) + ni * 16 + lane15;
          tp[nl][ml] = f2bf(acc[mi][ni][r] + bias[bn * BN + nl]);
        }
    __syncthreads();
    int nl = tid >> 1, half = tid & 1;    // nl 0..127, half covers 64 s each
    int h = (bn - 4) * 4 + (nl >> 5), d = nl & 31;
    int b = bm >> 4, sc = bm & 15;        // 128-row s-chunk within batch
    int bh = b * 16 + h;
    uint4 v4[8];
    float ssum = 0.f;
    #pragma unroll
    for (int p = 0; p < 8; ++p){
      v4[p] = *(const uint4*)&tp[nl][half * 64 + p * 8];
      const unsigned* w = (const unsigned*)&v4[p];
      #pragma unroll
      for (int j = 0; j < 4; ++j)
        ssum += bf2f((unsigned short)(w[j] & 0xffff)) + bf2f((unsigned short)(w[j] >> 16));
    }
    ssum += __shfl_xor(ssum, 1);          // combine the two halves
    size_t vtoff = (size_t)(bh * HDIM + d) * SEQ + sc * 128 + half * 64;
    #pragma unroll
    for (int p = 0; p < 8; ++p) *(uint4*)(vt + vtoff + p * 8) = v4[p];
    if (half == 0) vsum_p[(sc * 32 + bh) * HDIM + d] = ssum;
  } else {
    #pragma unroll
    for (int mi = 0; mi < MF; ++mi){
      #pragma unroll
      for (int ni = 0; ni < NF; ++ni){
        #pragma unroll
        for (int r = 0; r < 4; ++r){
          int m = bm * BM + wm * (BM / 2) + mi * 16 + laneh * 4 + r;
          int nloc = wn * (BN / 2) + ni * 16 + lane15;
          int n = bn * BN + nloc;
          float val = acc[mi][ni][r] + bias[n];
          if (MODE == 0){
            // head-major q/k: [bh][s][32]
            int b = m >> 11, s = m & 2047;
            int h = n >> 5, d = n & 31;
            size_t idx = ((size_t)(b * 16 + h) * SEQ + s) * HDIM + d;
            float sv = val / (1.0f + __expf(-val)) * QSCALE;      // silu * scale
            float tv = 1.0f - 2.0f / (1.0f + __expf(2.0f * val)); // tanh
            qb[idx] = f2bf(sv);
            kb[idx] = f2bf(tv);
          } else {
            size_t idx = (size_t)m * DIMX + n;
            yb[idx] = f2bf(val + bf2f(xb[idx]));
          }
        }
      }
    }
  }
}

// ---------- K3: banded attention (e^s - 1 trick), MFMA, 9 k-tiles ----------
// q/k head-major [bh][s][32]: fully coalesced 1KB loads per instr.
__launch_bounds__(256)
__global__ void k_attn(const unsigned short* __restrict__ qb,
                       const unsigned short* __restrict__ kb,
                       const unsigned short* __restrict__ vt,
                       const float* __restrict__ vsum_p,
                       unsigned short* __restrict__ ao)
{
  __shared__ unsigned short p_lds[4][16][40];   // per-wave P staging, padded
  int tid = threadIdx.x, wid = tid >> 6, lane = tid & 63;
  int lane15 = lane & 15, laneh = lane >> 4;
  int bh = blockIdx.y, b = bh >> 4, h = bh & 15;
  int s0 = blockIdx.x * 64 + wid * 16;

  bf16x8 qf = *(const bf16x8*)(qb + ((size_t)bh * SEQ + s0 + lane15) * HDIM + laneh * 8);
  float vs0 = 0.f, vs1 = 0.f;
  #pragma unroll
  for (int c = 0; c < 16; ++c){
    vs0 += vsum_p[(c * 32 + bh) * HDIM + lane15];
    vs1 += vsum_p[(c * 32 + bh) * HDIM + 16 + lane15];
  }

  f32x4 accv[2] = {};
  float dsum[4] = {0.f, 0.f, 0.f, 0.f};

  // band |i-j|<=64 with i in [s0, s0+16) touches j in [s0-64, s0+80) = 9 tiles
  for (int jt = 0; jt < 9; ++jt){
    int j0 = s0 - 64 + jt * 16;
    int jc = min(max(j0 + lane15, 0), SEQ - 1);
    bf16x8 kf = *(const bf16x8*)(kb + ((size_t)bh * SEQ + jc) * HDIM + laneh * 8);
    f32x4 z = {0.f, 0.f, 0.f, 0.f};
    f32x4 sv = __builtin_amdgcn_mfma_f32_16x16x32_bf16(qf, kf, z, 0, 0, 0);
    #pragma unroll
    for (int r = 0; r < 4; ++r){
      int i = s0 + laneh * 4 + r;
      int j = j0 + lane15;
      int dj = i - j;
      bool inb = (dj <= WIN) && (dj >= -WIN) && (j >= 0) && (j < SEQ);
      float w = inb ? (__expf(sv[r]) - 1.0f) : 0.0f;
      dsum[r] += w;
      p_lds[wid][laneh * 4 + r][(jt & 1) * 16 + lane15] = f2bf(w);
    }
    if (jt & 1){
      int jc0 = j0 - 16;   // 32-wide chunk base
      bf16x8 pa = *(const bf16x8*)&p_lds[wid][lane15][laneh * 8];
      int jv = min(max(jc0 + laneh * 8, 0), SEQ - 8);
      bf16x8 v0 = *(const bf16x8*)(vt + (size_t)(bh * HDIM + lane15) * SEQ + jv);
      bf16x8 v1 = *(const bf16x8*)(vt + (size_t)(bh * HDIM + 16 + lane15) * SEQ + jv);
      accv[0] = __builtin_amdgcn_mfma_f32_16x16x32_bf16(pa, v0, accv[0], 0, 0, 0);
      accv[1] = __builtin_amdgcn_mfma_f32_16x16x32_bf16(pa, v1, accv[1], 0, 0, 0);
    }
  }
  // tail PV for tile 8 (cols 0..15); zero cols 16..31 first
  {
    #pragma unroll
    for (int r = 0; r < 4; ++r)
      p_lds[wid][laneh * 4 + r][16 + lane15] = 0;
    int jc0 = s0 + 64;
    bf16x8 pa = *(const bf16x8*)&p_lds[wid][lane15][laneh * 8];
    int jv = min(max(jc0 + laneh * 8, 0), SEQ - 8);
    bf16x8 v0 = *(const bf16x8*)(vt + (size_t)(bh * HDIM + lane15) * SEQ + jv);
    bf16x8 v1 = *(const bf16x8*)(vt + (size_t)(bh * HDIM + 16 + lane15) * SEQ + jv);
    accv[0] = __builtin_amdgcn_mfma_f32_16x16x32_bf16(pa, v0, accv[0], 0, 0, 0);
    accv[1] = __builtin_amdgcn_mfma_f32_16x16x32_bf16(pa, v1, accv[1], 0, 0, 0);
  }

  #pragma unroll
  for (int r = 0; r < 4; ++r){
    float v = dsum[r];
    v += __shfl_xor(v, 1); v += __shfl_xor(v, 2);
    v += __shfl_xor(v, 4); v += __shfl_xor(v, 8);
    dsum[r] = v;
  }
  #pragma unroll
  for (int r = 0; r < 4; ++r){
    int i = s0 + laneh * 4 + r;
    float dn = (float)SEQ + dsum[r];
    float o0 = (accv[0][r] + vs0) / dn;
    float o1 = (accv[1][r] + vs1) / dn;
    size_t base = (size_t)(b * SEQ + i) * DIMX + h * HDIM;
    ao[base + lane15]      = f2bf(o0);
    ao[base + 16 + lane15] = f2bf(o1);
  }
}

// ---------- K5: LayerNorm over 512 (bf16 in, fp32 out), one wave per row ----------
__global__ void k_ln(const unsigned short* __restrict__ yb, const float* __restrict__ gamma,
                     const float* __restrict__ beta, float* __restrict__ out){
  int wid = threadIdx.x >> 6, lane = threadIdx.x & 63;
  int row = blockIdx.x * 4 + wid;
  uint4 u = *(const uint4*)(yb + (size_t)row * DIMX + lane * 8);
  const unsigned* w = (const unsigned*)&u;
  float v[8];
  #pragma unroll
  for (int j = 0; j < 4; ++j){
    v[2*j]   = bf2f((unsigned short)(w[j] & 0xffff));
    v[2*j+1] = bf2f((unsigned short)(w[j] >> 16));
  }
  float s = 0.f, ss = 0.f;
  #pragma unroll
  for (int j = 0; j < 8; ++j){ s += v[j]; ss += v[j] * v[j]; }
  #pragma unroll
  for (int m = 1; m < 64; m <<= 1){ s += __shfl_xor(s, m); ss += __shfl_xor(ss, m); }
  float mu = s * (1.f / DIMX);
  float var = ss * (1.f / DIMX) - mu * mu;
  float inv = rsqrtf(var + 1e-5f);
  float4 g0 = *(const float4*)(gamma + lane * 8);
  float4 g1 = *(const float4*)(gamma + lane * 8 + 4);
  float4 b0 = *(const float4*)(beta + lane * 8);
  float4 b1 = *(const float4*)(beta + lane * 8 + 4);
  float4 o0, o1;
  o0.x = (v[0] - mu) * inv * g0.x + b0.x; o0.y = (v[1] - mu) * inv * g0.y + b0.y;
  o0.z = (v[2] - mu) * inv * g0.z + b0.z; o0.w = (v[3] - mu) * inv * g0.w + b0.w;
  o1.x = (v[4] - mu) * inv * g1.x + b1.x; o1.y = (v[5] - mu) * inv * g1.y + b1.y;
  o1.z = (v[6] - mu) * inv * g1.z + b1.z; o1.w = (v[7] - mu) * inv * g1.w + b1.w;
  float* op = out + (size_t)row * DIMX + lane * 8;
  *(float4*)op = o0; *(float4*)(op + 4) = o1;
}

extern "C" void kernel_launch(void* const* d_in, const int* in_sizes, int n_in,
                              void* d_out, int out_size, void* d_ws, size_t ws_size,
                              hipStream_t stream){
  const float* x      = (const float*)d_in[0];
  const float* W_qkv  = (const float*)d_in[1];
  const float* b_qkv  = (const float*)d_in[2];
  const float* W_out  = (const float*)d_in[3];
  const float* b_out  = (const float*)d_in[4];
  const float* gamma  = (const float*)d_in[5];
  const float* beta   = (const float*)d_in[6];
  float* out = (float*)d_out;

  char* ws = (char*)d_ws;
  size_t off = 0;
  auto alloc = [&](size_t bytes){ void* p = ws + off; off += (bytes + 255) & ~(size_t)255; return p; };
  unsigned short* xb  = (unsigned short*)alloc((size_t)MTOT * DIMX * 2);
  unsigned short* wqt = (unsigned short*)alloc((size_t)1024 * 512 * 2);
  unsigned short* wot = (unsigned short*)alloc((size_t)512 * 512 * 2);
  unsigned short* qb  = (unsigned short*)alloc((size_t)MTOT * DIMX * 2);
  unsigned short* kb  = (unsigned short*)alloc((size_t)MTOT * DIMX * 2);
  unsigned short* vt  = (unsigned short*)alloc((size_t)32 * HDIM * SEQ * 2);
  float*          vsm = (float*)alloc((size_t)16 * 32 * HDIM * 4);
  unsigned short* ao  = (unsigned short*)alloc((size_t)MTOT * DIMX * 2);
  unsigned short* yb  = (unsigned short*)alloc((size_t)MTOT * DIMX * 2);

  k_prep<<<1792, 256, 0, stream>>>(x, xb, W_qkv, wqt, W_out, wot);
  k_gemm<0, 128, 128, 8><<<256, 256, 0, stream>>>(xb, wqt, b_qkv, qb, kb, vt, vsm, nullptr, nullptr);
  k_attn<<<dim3(32, 32), 256, 0, stream>>>(qb, kb, vt, vsm, ao);
  k_gemm<1, 64, 64, 8><<<512, 256, 0, stream>>>(ao, wot, b_out, nullptr, nullptr, nullptr, nullptr, xb, yb);
  k_ln  <<<MTOT / 4, 256, 0, stream>>>(yb, gamma, beta, out);
}